// Round 3
// baseline (1781.141 us; speedup 1.0000x reference)
//
#include <hip/hip_runtime.h>
#include <hip/hip_bf16.h>
#include <stdint.h>

// Model dims: L=4, D=1024, H=16, G=4, HS=64, I=2816, V=32000, B=4, T=512. NT = 2048.
// Inputs: f32 (+ int32 ids). Output: f32 logits [B,T,V].

typedef __bf16 bf16x8 __attribute__((ext_vector_type(8)));
typedef __bf16 bf16x4 __attribute__((ext_vector_type(4)));
typedef float  f32x4  __attribute__((ext_vector_type(4)));

#define AS1 __attribute__((address_space(1)))
#define AS3 __attribute__((address_space(3)))

// global -> LDS direct copy, 16B per lane. LDS dest must be wave-uniform base + lane*16.
__device__ __forceinline__ void gld_lds16(const void* g, void* l) {
  __builtin_amdgcn_global_load_lds((const AS1 void*)g, (AS3 void*)l, 16, 0, 0);
}

// ---------------- embedding lookup: x_f32[tok, :] = embed_f32[ids[tok], :] ----------------
__global__ __launch_bounds__(256) void embed_kernel(const int* __restrict__ ids,
                                                    const float* __restrict__ emb,
                                                    float* __restrict__ x) {
  const int tok = blockIdx.x;
  const float* src = emb + (size_t)ids[tok] * 1024;
  float* dst = x + (size_t)tok * 1024;
#pragma unroll
  for (int j = 0; j < 4; ++j) {
    const int d = threadIdx.x + j * 256;
    dst[d] = src[d];
  }
}

// ---------------- RMSNorm: out_bf16[row,:] = x*rsqrt(mean(x^2)+eps)*w ----------------
__global__ __launch_bounds__(256) void rmsnorm_kernel(const float* __restrict__ x,
                                                      const float* __restrict__ wgt,
                                                      __bf16* __restrict__ out) {
  const int row = blockIdx.x;
  const float* xr = x + (size_t)row * 1024;
  float v[4];
  float ss = 0.f;
#pragma unroll
  for (int j = 0; j < 4; ++j) { v[j] = xr[threadIdx.x + j * 256]; ss += v[j] * v[j]; }
#pragma unroll
  for (int m = 1; m < 64; m <<= 1) ss += __shfl_xor(ss, m, 64);
  __shared__ float red[4];
  if ((threadIdx.x & 63) == 0) red[threadIdx.x >> 6] = ss;
  __syncthreads();
  const float tot = red[0] + red[1] + red[2] + red[3];
  const float sc = rsqrtf(tot * (1.f / 1024.f) + 1e-6f);
#pragma unroll
  for (int j = 0; j < 4; ++j) {
    const int d = threadIdx.x + j * 256;
    out[(size_t)row * 1024 + d] = (__bf16)(v[j] * sc * wgt[d]);
  }
}

// ---------------- GEMM: C[M,N] = A[M,K](bf16) * B[N,K](f32)^T ----------------
// 128x128 tile, BK=32, 256 threads = 4 waves (2x2), each wave 64x64 via 4x4 MFMA frags.
// B (weights) is read as f32 and converted to bf16 during LDS staging.
// EPI: 0 = store bf16, 1 = +bias(f32) store bf16, 2 = accumulate into f32 C, 3 = store f32.
template <int EPI>
__global__ __launch_bounds__(256) void gemm_bt(const __bf16* __restrict__ A,
                                               const float* __restrict__ Bw,
                                               const float* __restrict__ bias,
                                               __bf16* __restrict__ Cb,
                                               float* __restrict__ Cf,
                                               int K, int ldc) {
  __shared__ __bf16 As[128 * 32];
  __shared__ __bf16 Bs[128 * 32];
  const int t = threadIdx.x;
  const int lane = t & 63;
  const int w = t >> 6, wr = w >> 1, wc = w & 1;
  const int bm = blockIdx.y, bn = blockIdx.x;

  // A staging: global_load_lds, 16B/lane
  const int sr = t >> 2;        // staging row within 64-row half
  const int scol = (t & 3) * 8; // staging col (bf16 elems)
  const __bf16* a0 = A + (size_t)(bm * 128 + sr) * K + scol;
  const __bf16* a1 = A + (size_t)(bm * 128 + 64 + sr) * K + scol;

  // B staging: f32 loads + in-register cvt + ds_write (4 rounds of 32 rows)
  const int br = t >> 3;        // 0..31
  const int bc = (t & 7) * 4;   // f32 col 0,4,..,28
  const float* bsrc = Bw + (size_t)(bn * 128 + br) * K + bc;

  f32x4 acc[4][4] = {};

  const int lr = lane & 15;       // fragment row (M for A, N for B)
  const int lk = (lane >> 4) * 8; // fragment K offset

  for (int k0 = 0; k0 < K; k0 += 32) {
    gld_lds16(a0 + k0, &As[t * 8]);
    gld_lds16(a1 + k0, &As[2048 + t * 8]);
#pragma unroll
    for (int j = 0; j < 4; ++j) {
      f32x4 v = *(const f32x4*)(bsrc + (size_t)(j * 32) * K + k0);
      bf16x4 o;
#pragma unroll
      for (int jj = 0; jj < 4; ++jj) o[jj] = (__bf16)v[jj];
      *(bf16x4*)&Bs[(br + j * 32) * 32 + bc] = o;
    }
    __syncthreads();
    bf16x8 af[4], bfr[4];
#pragma unroll
    for (int m = 0; m < 4; ++m) af[m] = *(const bf16x8*)&As[(wr * 64 + m * 16 + lr) * 32 + lk];
#pragma unroll
    for (int n = 0; n < 4; ++n) bfr[n] = *(const bf16x8*)&Bs[(wc * 64 + n * 16 + lr) * 32 + lk];
#pragma unroll
    for (int m = 0; m < 4; ++m)
#pragma unroll
      for (int n = 0; n < 4; ++n)
        acc[m][n] = __builtin_amdgcn_mfma_f32_16x16x32_bf16(af[m], bfr[n], acc[m][n], 0, 0, 0);
    __syncthreads();
  }

  // C/D layout: col = lane&15, row = (lane>>4)*4 + reg   [learn_hip m89]
  const int r0 = bm * 128 + wr * 64 + (lane >> 4) * 4;
  const int c0 = bn * 128 + wc * 64 + lr;
  if (EPI == 2 || EPI == 3) {
#pragma unroll
    for (int m = 0; m < 4; ++m)
#pragma unroll
      for (int r = 0; r < 4; ++r) {
        const size_t rowoff = (size_t)(r0 + m * 16 + r) * ldc;
#pragma unroll
        for (int n = 0; n < 4; ++n) {
          if (EPI == 2) Cf[rowoff + c0 + n * 16] += acc[m][n][r];
          else          Cf[rowoff + c0 + n * 16] = acc[m][n][r];
        }
      }
  } else {
    float bv[4] = {0.f, 0.f, 0.f, 0.f};
    if (EPI == 1) {
#pragma unroll
      for (int n = 0; n < 4; ++n) bv[n] = bias[bn * 128 + wc * 64 + n * 16 + lr];
    }
#pragma unroll
    for (int m = 0; m < 4; ++m)
#pragma unroll
      for (int r = 0; r < 4; ++r) {
        const size_t rowoff = (size_t)(r0 + m * 16 + r) * ldc;
#pragma unroll
        for (int n = 0; n < 4; ++n) Cb[rowoff + c0 + n * 16] = (__bf16)(acc[m][n][r] + bv[n]);
      }
  }
}

// ---------------- RoPE in place on q [tok, 16*64] and k half of kv [tok, 512] ----------------
__global__ __launch_bounds__(256) void rope_kernel(__bf16* __restrict__ q,
                                                   __bf16* __restrict__ kv) {
  const int tok = blockIdx.x;
  const float tpos = (float)(tok & 511);
  for (int p = threadIdx.x; p < 640; p += 256) {  // 16 q-heads*32 pairs + 4 kv-groups*32 pairs
    const int i = p & 31;
    const float inv = expf((float)i * -0.28782313662425574f);  // 10000^(-i/32)
    float sg, cg;
    sincosf(tpos * inv, &sg, &cg);
    __bf16* base = (p < 512) ? (q + (size_t)tok * 1024 + (size_t)(p >> 5) * 64)
                             : (kv + (size_t)tok * 512 + (size_t)((p - 512) >> 5) * 64);
    const float x1 = (float)base[i], x2 = (float)base[i + 32];
    base[i] = (__bf16)(x1 * cg - x2 * sg);
    base[i + 32] = (__bf16)(x2 * cg + x1 * sg);
  }
}

// ---------------- causal GQA flash attention ----------------
// grid = (T/64, H, B), 256 threads = 4 waves; wave w owns 16 query rows.
__global__ __launch_bounds__(256) void attn_kernel(const __bf16* __restrict__ q,
                                                   const __bf16* __restrict__ kv,
                                                   __bf16* __restrict__ o) {
  const int qt = blockIdx.x, hh = blockIdx.y, b = blockIdx.z;
  const int g = hh >> 2;  // GQA group
  const int t = threadIdx.x, lane = t & 63, w = t >> 6;
  const int lr = lane & 15, lg = lane >> 4;

  __shared__ __bf16 Ks[64 * 64];
  __shared__ __bf16 Vt[64 * 64];  // transposed: Vt[d][k]
  __shared__ __bf16 Ps[64 * 64];

  bf16x8 qa[2];
  {
    const size_t qoff = ((size_t)(b * 512 + qt * 64 + w * 16 + lr)) * 1024 + hh * 64;
    qa[0] = *(const bf16x8*)(q + qoff + lg * 8);
    qa[1] = *(const bf16x8*)(q + qoff + 32 + lg * 8);
  }

  f32x4 acc_o[4] = {};
  float mrow[4], lrow[4];
#pragma unroll
  for (int r = 0; r < 4; ++r) { mrow[r] = -1e30f; lrow[r] = 0.f; }

  const int srow = t >> 3;        // staging row 0..31
  const int sd = (t & 7) * 8;     // staging col

  for (int kt = 0; kt <= qt; ++kt) {
    const size_t krow = ((size_t)(b * 512 + kt * 64 + srow)) * 512;
    gld_lds16(kv + krow + g * 64 + sd, &Ks[t * 8]);
    gld_lds16(kv + krow + 32 * 512 + g * 64 + sd, &Ks[2048 + t * 8]);
    {
      const __bf16* vsrc = kv + krow + 256 + g * 64 + sd;
      bf16x8 v0 = *(const bf16x8*)vsrc;
      bf16x8 v1 = *(const bf16x8*)(vsrc + 32 * 512);
#pragma unroll
      for (int j = 0; j < 8; ++j) Vt[(sd + j) * 64 + srow] = v0[j];
#pragma unroll
      for (int j = 0; j < 8; ++j) Vt[(sd + j) * 64 + srow + 32] = v1[j];
    }
    __syncthreads();

    // S = Q K^T for this wave's 16 q rows x 64 keys
    f32x4 s[4] = {};
#pragma unroll
    for (int nf = 0; nf < 4; ++nf)
#pragma unroll
      for (int kc = 0; kc < 2; ++kc) {
        bf16x8 kb = *(const bf16x8*)&Ks[(nf * 16 + lr) * 64 + kc * 32 + lg * 8];
        s[nf] = __builtin_amdgcn_mfma_f32_16x16x32_bf16(qa[kc], kb, s[nf], 0, 0, 0);
      }

    float pm[4][4], mx[4];
    const int qg = qt * 64 + w * 16 + lg * 4;
    const int kg = kt * 64 + lr;
#pragma unroll
    for (int r = 0; r < 4; ++r) mx[r] = -1e30f;
#pragma unroll
    for (int nf = 0; nf < 4; ++nf)
#pragma unroll
      for (int r = 0; r < 4; ++r) {
        float vv = s[nf][r] * 0.125f;
        vv = (kg + nf * 16 <= qg + r) ? vv : -1e30f;  // causal mask
        pm[nf][r] = vv;
        mx[r] = fmaxf(mx[r], vv);
      }
#pragma unroll
    for (int msk = 1; msk < 16; msk <<= 1)
#pragma unroll
      for (int r = 0; r < 4; ++r) mx[r] = fmaxf(mx[r], __shfl_xor(mx[r], msk, 64));

    float rs[4];
#pragma unroll
    for (int r = 0; r < 4; ++r) {
      const float mn = fmaxf(mrow[r], mx[r]);
      const float f = __expf(mrow[r] - mn);
      mrow[r] = mn;
      lrow[r] *= f;
#pragma unroll
      for (int df = 0; df < 4; ++df) acc_o[df][r] *= f;
      float rsum = 0.f;
#pragma unroll
      for (int nf = 0; nf < 4; ++nf) {
        const float pp = __expf(pm[nf][r] - mn);
        pm[nf][r] = pp;
        rsum += pp;
      }
      rs[r] = rsum;
    }
#pragma unroll
    for (int msk = 1; msk < 16; msk <<= 1)
#pragma unroll
      for (int r = 0; r < 4; ++r) rs[r] += __shfl_xor(rs[r], msk, 64);
#pragma unroll
    for (int r = 0; r < 4; ++r) lrow[r] += rs[r];

    // P -> LDS (C-layout -> A-layout round trip), per-wave private rows
#pragma unroll
    for (int nf = 0; nf < 4; ++nf)
#pragma unroll
      for (int r = 0; r < 4; ++r)
        Ps[(w * 16 + lg * 4 + r) * 64 + nf * 16 + lr] = (__bf16)pm[nf][r];

    // O += P V
#pragma unroll
    for (int df = 0; df < 4; ++df)
#pragma unroll
      for (int kc = 0; kc < 2; ++kc) {
        bf16x8 pa = *(const bf16x8*)&Ps[(w * 16 + lr) * 64 + kc * 32 + lg * 8];
        bf16x8 vb = *(const bf16x8*)&Vt[(df * 16 + lr) * 64 + kc * 32 + lg * 8];
        acc_o[df] = __builtin_amdgcn_mfma_f32_16x16x32_bf16(pa, vb, acc_o[df], 0, 0, 0);
      }
    __syncthreads();
  }

#pragma unroll
  for (int df = 0; df < 4; ++df)
#pragma unroll
    for (int r = 0; r < 4; ++r) {
      const int trow = qt * 64 + w * 16 + lg * 4 + r;
      o[((size_t)(b * 512 + trow)) * 1024 + hh * 64 + df * 16 + lr] =
          (__bf16)(acc_o[df][r] / lrow[r]);
    }
}

// ---------------- SwiGLU in place: g = silu(g) * u ----------------
__global__ __launch_bounds__(256) void swiglu_kernel(__bf16* __restrict__ gb,
                                                     const __bf16* __restrict__ ub, int n) {
  const int i = blockIdx.x * 256 + threadIdx.x;
  if (i < n) {
    const float gv = (float)gb[i], uv = (float)ub[i];
    gb[i] = (__bf16)(gv / (1.f + __expf(-gv)) * uv);
  }
}

extern "C" void kernel_launch(void* const* d_in, const int* in_sizes, int n_in,
                              void* d_out, int out_size, void* d_ws, size_t ws_size,
                              hipStream_t stream) {
  const int* ids = (const int*)d_in[0];
  const float* emb_f = (const float*)d_in[1];
  const float* qw_f = (const float*)d_in[2];
  const float* q_b = (const float*)d_in[3];
  const float* kvw_f = (const float*)d_in[4];
  const float* kv_b = (const float*)d_in[5];
  const float* ow_f = (const float*)d_in[6];
  const float* ln1 = (const float*)d_in[7];
  const float* ln2 = (const float*)d_in[8];
  const float* gw_f = (const float*)d_in[9];
  const float* uw_f = (const float*)d_in[10];
  const float* dw_f = (const float*)d_in[11];
  const float* lw = (const float*)d_in[12];
  float* out = (float*)d_out;  // f32 logits

  char* p = (char*)d_ws;
  float* x = (float*)p;        p += (size_t)2048 * 1024 * 4;  // f32 residual stream
  __bf16* h = (__bf16*)p;      p += (size_t)2048 * 1024 * 2;  // rmsnorm output
  __bf16* qb = (__bf16*)p;     p += (size_t)2048 * 1024 * 2;  // q proj
  __bf16* kvb = (__bf16*)p;    p += (size_t)2048 * 512 * 2;   // kv proj
  __bf16* ao = (__bf16*)p;     p += (size_t)2048 * 1024 * 2;  // attention out
  __bf16* gb = (__bf16*)p;     p += (size_t)2048 * 2816 * 2;  // gate (then swiglu result)
  __bf16* ub = (__bf16*)p;     p += (size_t)2048 * 2816 * 2;  // up

  embed_kernel<<<2048, 256, 0, stream>>>(ids, emb_f, x);
  for (int l = 0; l < 4; ++l) {
    rmsnorm_kernel<<<2048, 256, 0, stream>>>(x, ln1 + l * 1024, h);
    gemm_bt<1><<<dim3(8, 16), 256, 0, stream>>>(h, qw_f + (size_t)l * 1024 * 1024,
                                                q_b + l * 1024, qb, nullptr, 1024, 1024);
    gemm_bt<1><<<dim3(4, 16), 256, 0, stream>>>(h, kvw_f + (size_t)l * 512 * 1024,
                                                kv_b + l * 512, kvb, nullptr, 1024, 512);
    rope_kernel<<<2048, 256, 0, stream>>>(qb, kvb);
    attn_kernel<<<dim3(8, 16, 4), 256, 0, stream>>>(qb, kvb, ao);
    gemm_bt<2><<<dim3(8, 16), 256, 0, stream>>>(ao, ow_f + (size_t)l * 1024 * 1024,
                                                nullptr, nullptr, x, 1024, 1024);
    rmsnorm_kernel<<<2048, 256, 0, stream>>>(x, ln2 + l * 1024, h);
    gemm_bt<0><<<dim3(22, 16), 256, 0, stream>>>(h, gw_f + (size_t)l * 2816 * 1024,
                                                 nullptr, gb, nullptr, 1024, 2816);
    gemm_bt<0><<<dim3(22, 16), 256, 0, stream>>>(h, uw_f + (size_t)l * 2816 * 1024,
                                                 nullptr, ub, nullptr, 1024, 2816);
    const int nsw = 2048 * 2816;
    swiglu_kernel<<<(nsw + 255) / 256, 256, 0, stream>>>(gb, ub, nsw);
    gemm_bt<2><<<dim3(8, 16), 256, 0, stream>>>(gb, dw_f + (size_t)l * 1024 * 2816,
                                                nullptr, nullptr, x, 2816, 1024);
  }
  rmsnorm_kernel<<<2048, 256, 0, stream>>>(x, lw, h);
  gemm_bt<3><<<dim3(250, 16), 256, 0, stream>>>(h, emb_f, nullptr, nullptr, out, 1024, 32000);
}

// Round 4
// 1713.427 us; speedup vs baseline: 1.0395x; 1.0395x over previous
//
#include <hip/hip_runtime.h>
#include <hip/hip_bf16.h>
#include <stdint.h>

// Model dims: L=4, D=1024, H=16, G=4, HS=64, I=2816, V=32000, B=4, T=512. NT = 2048.
// Inputs: f32 (+ int32 ids). Output: f32 logits [B,T,V].

typedef __bf16 bf16x8 __attribute__((ext_vector_type(8)));
typedef __bf16 bf16x4 __attribute__((ext_vector_type(4)));
typedef float  f32x4  __attribute__((ext_vector_type(4)));

#define AS1 __attribute__((address_space(1)))
#define AS3 __attribute__((address_space(3)))

// global -> LDS direct copy, 16B per lane. LDS dest must be wave-uniform base + lane*16.
__device__ __forceinline__ void gld_lds16(const void* g, void* l) {
  __builtin_amdgcn_global_load_lds((const AS1 void*)g, (AS3 void*)l, 16, 0, 0);
}

// ---------------- f32 -> bf16 convert (vectorized, grid-stride) ----------------
__global__ __launch_bounds__(256) void cvt_kernel(const float* __restrict__ in,
                                                  __bf16* __restrict__ out, int n4) {
  for (int i = blockIdx.x * 256 + threadIdx.x; i < n4; i += gridDim.x * 256) {
    f32x4 v = ((const f32x4*)in)[i];
    bf16x4 o;
#pragma unroll
    for (int j = 0; j < 4; ++j) o[j] = (__bf16)v[j];
    ((bf16x4*)out)[i] = o;
  }
}

// ---------------- embedding lookup: x_f32[tok, :] = embed_f32[ids[tok], :] ----------------
__global__ __launch_bounds__(256) void embed_kernel(const int* __restrict__ ids,
                                                    const float* __restrict__ emb,
                                                    float* __restrict__ x) {
  const int tok = blockIdx.x;
  const float* src = emb + (size_t)ids[tok] * 1024;
  float* dst = x + (size_t)tok * 1024;
#pragma unroll
  for (int j = 0; j < 4; ++j) {
    const int d = threadIdx.x + j * 256;
    dst[d] = src[d];
  }
}

// ---------------- RMSNorm: out_bf16[row,:] = x*rsqrt(mean(x^2)+eps)*w ----------------
__global__ __launch_bounds__(256) void rmsnorm_kernel(const float* __restrict__ x,
                                                      const float* __restrict__ wgt,
                                                      __bf16* __restrict__ out) {
  const int row = blockIdx.x;
  const float* xr = x + (size_t)row * 1024;
  float v[4];
  float ss = 0.f;
#pragma unroll
  for (int j = 0; j < 4; ++j) { v[j] = xr[threadIdx.x + j * 256]; ss += v[j] * v[j]; }
#pragma unroll
  for (int m = 1; m < 64; m <<= 1) ss += __shfl_xor(ss, m, 64);
  __shared__ float red[4];
  if ((threadIdx.x & 63) == 0) red[threadIdx.x >> 6] = ss;
  __syncthreads();
  const float tot = red[0] + red[1] + red[2] + red[3];
  const float sc = rsqrtf(tot * (1.f / 1024.f) + 1e-6f);
#pragma unroll
  for (int j = 0; j < 4; ++j) {
    const int d = threadIdx.x + j * 256;
    out[(size_t)row * 1024 + d] = (__bf16)(v[j] * sc * wgt[d]);
  }
}

// ---------------- GEMM: C[M,N] = A[M,K](bf16) * B[N,K]^T ----------------
// 128x128 tile, BK=32, 256 threads = 4 waves (2x2), each wave 64x64 via 4x4 MFMA frags.
// BB16: B is bf16 (global_load_lds staging) else f32 (load+cvt staging).
// SWZ: flat 1-D grid, XCD-chunked swizzle, bm-inner (for big-N GEMMs; requires grid%8==0).
// EPI: 0 = store bf16, 1 = +bias(f32) store bf16, 2 = accumulate into f32 C, 3 = store f32.
template <int EPI, bool BB16, bool SWZ>
__global__ __launch_bounds__(256) void gemm_bt(const __bf16* __restrict__ A,
                                               const float* __restrict__ Bw,
                                               const __bf16* __restrict__ Bb,
                                               const float* __restrict__ bias,
                                               __bf16* __restrict__ Cb,
                                               float* __restrict__ Cf,
                                               int K, int ldc) {
  __shared__ __bf16 As[128 * 32];
  __shared__ __bf16 Bs[128 * 32];
  const int t = threadIdx.x;
  const int lane = t & 63;
  const int w = t >> 6, wr = w >> 1, wc = w & 1;

  int bm, bn;
  if (SWZ) {
    // bijective XCD-chunked remap: 8 XCDs, each owns a contiguous wg range; bm inner.
    const int bid = blockIdx.x;
    const int chunk = gridDim.x >> 3;  // grid % 8 == 0
    const int wg = (bid & 7) * chunk + (bid >> 3);
    bm = wg & 15;   // M/128 == 16
    bn = wg >> 4;
  } else {
    bm = blockIdx.y;
    bn = blockIdx.x;
  }

  // A staging: global_load_lds, 16B/lane
  const int sr = t >> 2;        // staging row within 64-row half
  const int scol = (t & 3) * 8; // staging col (bf16 elems)
  const __bf16* a0 = A + (size_t)(bm * 128 + sr) * K + scol;
  const __bf16* a1 = A + (size_t)(bm * 128 + 64 + sr) * K + scol;

  // B staging (f32 path): f32 loads + in-register cvt + ds_write (4 rounds of 32 rows)
  const int br = t >> 3;        // 0..31
  const int bc = (t & 7) * 4;   // f32 col 0,4,..,28
  const float* bsrc = BB16 ? nullptr : (Bw + (size_t)(bn * 128 + br) * K + bc);
  // B staging (bf16 path)
  const __bf16* bb0 = BB16 ? (Bb + (size_t)(bn * 128 + sr) * K + scol) : nullptr;
  const __bf16* bb1 = BB16 ? (Bb + (size_t)(bn * 128 + 64 + sr) * K + scol) : nullptr;

  f32x4 acc[4][4] = {};

  const int lr = lane & 15;       // fragment row (M for A, N for B)
  const int lk = (lane >> 4) * 8; // fragment K offset

  for (int k0 = 0; k0 < K; k0 += 32) {
    gld_lds16(a0 + k0, &As[t * 8]);
    gld_lds16(a1 + k0, &As[2048 + t * 8]);
    if (BB16) {
      gld_lds16(bb0 + k0, &Bs[t * 8]);
      gld_lds16(bb1 + k0, &Bs[2048 + t * 8]);
    } else {
#pragma unroll
      for (int j = 0; j < 4; ++j) {
        f32x4 v = *(const f32x4*)(bsrc + (size_t)(j * 32) * K + k0);
        bf16x4 o;
#pragma unroll
        for (int jj = 0; jj < 4; ++jj) o[jj] = (__bf16)v[jj];
        *(bf16x4*)&Bs[(br + j * 32) * 32 + bc] = o;
      }
    }
    __syncthreads();
    bf16x8 af[4], bfr[4];
#pragma unroll
    for (int m = 0; m < 4; ++m) af[m] = *(const bf16x8*)&As[(wr * 64 + m * 16 + lr) * 32 + lk];
#pragma unroll
    for (int n = 0; n < 4; ++n) bfr[n] = *(const bf16x8*)&Bs[(wc * 64 + n * 16 + lr) * 32 + lk];
#pragma unroll
    for (int m = 0; m < 4; ++m)
#pragma unroll
      for (int n = 0; n < 4; ++n)
        acc[m][n] = __builtin_amdgcn_mfma_f32_16x16x32_bf16(af[m], bfr[n], acc[m][n], 0, 0, 0);
    __syncthreads();
  }

  // C/D layout: col = lane&15, row = (lane>>4)*4 + reg   [learn_hip m89]
  const int r0 = bm * 128 + wr * 64 + (lane >> 4) * 4;
  const int c0 = bn * 128 + wc * 64 + lr;
  if (EPI == 2 || EPI == 3) {
#pragma unroll
    for (int m = 0; m < 4; ++m)
#pragma unroll
      for (int r = 0; r < 4; ++r) {
        const size_t rowoff = (size_t)(r0 + m * 16 + r) * ldc;
#pragma unroll
        for (int n = 0; n < 4; ++n) {
          if (EPI == 2) Cf[rowoff + c0 + n * 16] += acc[m][n][r];
          else          Cf[rowoff + c0 + n * 16] = acc[m][n][r];
        }
      }
  } else {
    float bv[4] = {0.f, 0.f, 0.f, 0.f};
    if (EPI == 1) {
#pragma unroll
      for (int n = 0; n < 4; ++n) bv[n] = bias[bn * 128 + wc * 64 + n * 16 + lr];
    }
#pragma unroll
    for (int m = 0; m < 4; ++m)
#pragma unroll
      for (int r = 0; r < 4; ++r) {
        const size_t rowoff = (size_t)(r0 + m * 16 + r) * ldc;
#pragma unroll
        for (int n = 0; n < 4; ++n) Cb[rowoff + c0 + n * 16] = (__bf16)(acc[m][n][r] + bv[n]);
      }
  }
}

// ---------------- RoPE in place on q [tok, 16*64] and k half of kv [tok, 512] ----------------
__global__ __launch_bounds__(256) void rope_kernel(__bf16* __restrict__ q,
                                                   __bf16* __restrict__ kv) {
  const int tok = blockIdx.x;
  const float tpos = (float)(tok & 511);
  for (int p = threadIdx.x; p < 640; p += 256) {  // 16 q-heads*32 pairs + 4 kv-groups*32 pairs
    const int i = p & 31;
    const float inv = __expf((float)i * -0.28782313662425574f);  // 10000^(-i/32)
    float sg, cg;
    __sincosf(tpos * inv, &sg, &cg);
    __bf16* base = (p < 512) ? (q + (size_t)tok * 1024 + (size_t)(p >> 5) * 64)
                             : (kv + (size_t)tok * 512 + (size_t)((p - 512) >> 5) * 64);
    const float x1 = (float)base[i], x2 = (float)base[i + 32];
    base[i] = (__bf16)(x1 * cg - x2 * sg);
    base[i + 32] = (__bf16)(x2 * cg + x1 * sg);
  }
}

// ---------------- causal GQA flash attention ----------------
// grid = (T/64, H, B), 256 threads = 4 waves; wave w owns 16 query rows.
__global__ __launch_bounds__(256) void attn_kernel(const __bf16* __restrict__ q,
                                                   const __bf16* __restrict__ kv,
                                                   __bf16* __restrict__ o) {
  const int qt = blockIdx.x, hh = blockIdx.y, b = blockIdx.z;
  const int g = hh >> 2;  // GQA group
  const int t = threadIdx.x, lane = t & 63, w = t >> 6;
  const int lr = lane & 15, lg = lane >> 4;

  __shared__ __bf16 Ks[64 * 64];
  __shared__ __bf16 Vt[64 * 64];  // transposed: Vt[d][k]
  __shared__ __bf16 Ps[64 * 64];

  bf16x8 qa[2];
  {
    const size_t qoff = ((size_t)(b * 512 + qt * 64 + w * 16 + lr)) * 1024 + hh * 64;
    qa[0] = *(const bf16x8*)(q + qoff + lg * 8);
    qa[1] = *(const bf16x8*)(q + qoff + 32 + lg * 8);
  }

  f32x4 acc_o[4] = {};
  float mrow[4], lrow[4];
#pragma unroll
  for (int r = 0; r < 4; ++r) { mrow[r] = -1e30f; lrow[r] = 0.f; }

  const int srow = t >> 3;        // staging row 0..31
  const int sd = (t & 7) * 8;     // staging col

  for (int kt = 0; kt <= qt; ++kt) {
    const size_t krow = ((size_t)(b * 512 + kt * 64 + srow)) * 512;
    gld_lds16(kv + krow + g * 64 + sd, &Ks[t * 8]);
    gld_lds16(kv + krow + 32 * 512 + g * 64 + sd, &Ks[2048 + t * 8]);
    {
      const __bf16* vsrc = kv + krow + 256 + g * 64 + sd;
      bf16x8 v0 = *(const bf16x8*)vsrc;
      bf16x8 v1 = *(const bf16x8*)(vsrc + 32 * 512);
#pragma unroll
      for (int j = 0; j < 8; ++j) Vt[(sd + j) * 64 + srow] = v0[j];
#pragma unroll
      for (int j = 0; j < 8; ++j) Vt[(sd + j) * 64 + srow + 32] = v1[j];
    }
    __syncthreads();

    // S = Q K^T for this wave's 16 q rows x 64 keys
    f32x4 s[4] = {};
#pragma unroll
    for (int nf = 0; nf < 4; ++nf)
#pragma unroll
      for (int kc = 0; kc < 2; ++kc) {
        bf16x8 kb = *(const bf16x8*)&Ks[(nf * 16 + lr) * 64 + kc * 32 + lg * 8];
        s[nf] = __builtin_amdgcn_mfma_f32_16x16x32_bf16(qa[kc], kb, s[nf], 0, 0, 0);
      }

    float pm[4][4], mx[4];
    const int qg = qt * 64 + w * 16 + lg * 4;
    const int kg = kt * 64 + lr;
#pragma unroll
    for (int r = 0; r < 4; ++r) mx[r] = -1e30f;
#pragma unroll
    for (int nf = 0; nf < 4; ++nf)
#pragma unroll
      for (int r = 0; r < 4; ++r) {
        float vv = s[nf][r] * 0.125f;
        vv = (kg + nf * 16 <= qg + r) ? vv : -1e30f;  // causal mask
        pm[nf][r] = vv;
        mx[r] = fmaxf(mx[r], vv);
      }
#pragma unroll
    for (int msk = 1; msk < 16; msk <<= 1)
#pragma unroll
      for (int r = 0; r < 4; ++r) mx[r] = fmaxf(mx[r], __shfl_xor(mx[r], msk, 64));

    float rs[4];
#pragma unroll
    for (int r = 0; r < 4; ++r) {
      const float mn = fmaxf(mrow[r], mx[r]);
      const float f = __expf(mrow[r] - mn);
      mrow[r] = mn;
      lrow[r] *= f;
#pragma unroll
      for (int df = 0; df < 4; ++df) acc_o[df][r] *= f;
      float rsum = 0.f;
#pragma unroll
      for (int nf = 0; nf < 4; ++nf) {
        const float pp = __expf(pm[nf][r] - mn);
        pm[nf][r] = pp;
        rsum += pp;
      }
      rs[r] = rsum;
    }
#pragma unroll
    for (int msk = 1; msk < 16; msk <<= 1)
#pragma unroll
      for (int r = 0; r < 4; ++r) rs[r] += __shfl_xor(rs[r], msk, 64);
#pragma unroll
    for (int r = 0; r < 4; ++r) lrow[r] += rs[r];

    // P -> LDS (C-layout -> A-layout round trip), per-wave private rows
#pragma unroll
    for (int nf = 0; nf < 4; ++nf)
#pragma unroll
      for (int r = 0; r < 4; ++r)
        Ps[(w * 16 + lg * 4 + r) * 64 + nf * 16 + lr] = (__bf16)pm[nf][r];

    // O += P V
#pragma unroll
    for (int df = 0; df < 4; ++df)
#pragma unroll
      for (int kc = 0; kc < 2; ++kc) {
        bf16x8 pa = *(const bf16x8*)&Ps[(w * 16 + lr) * 64 + kc * 32 + lg * 8];
        bf16x8 vb = *(const bf16x8*)&Vt[(df * 16 + lr) * 64 + kc * 32 + lg * 8];
        acc_o[df] = __builtin_amdgcn_mfma_f32_16x16x32_bf16(pa, vb, acc_o[df], 0, 0, 0);
      }
    __syncthreads();
  }

#pragma unroll
  for (int df = 0; df < 4; ++df)
#pragma unroll
    for (int r = 0; r < 4; ++r) {
      const int trow = qt * 64 + w * 16 + lg * 4 + r;
      o[((size_t)(b * 512 + trow)) * 1024 + hh * 64 + df * 16 + lr] =
          (__bf16)(acc_o[df][r] / lrow[r]);
    }
}

// ---------------- SwiGLU in place: g = silu(g) * u ----------------
__global__ __launch_bounds__(256) void swiglu_kernel(__bf16* __restrict__ gb,
                                                     const __bf16* __restrict__ ub, int n) {
  const int i = blockIdx.x * 256 + threadIdx.x;
  if (i < n) {
    const float gv = (float)gb[i], uv = (float)ub[i];
    gb[i] = (__bf16)(gv / (1.f + __expf(-gv)) * uv);
  }
}

extern "C" void kernel_launch(void* const* d_in, const int* in_sizes, int n_in,
                              void* d_out, int out_size, void* d_ws, size_t ws_size,
                              hipStream_t stream) {
  const int* ids = (const int*)d_in[0];
  const float* emb_f = (const float*)d_in[1];
  const float* qw_f = (const float*)d_in[2];
  const float* q_b = (const float*)d_in[3];
  const float* kvw_f = (const float*)d_in[4];
  const float* kv_b = (const float*)d_in[5];
  const float* ow_f = (const float*)d_in[6];
  const float* ln1 = (const float*)d_in[7];
  const float* ln2 = (const float*)d_in[8];
  const float* gw_f = (const float*)d_in[9];
  const float* uw_f = (const float*)d_in[10];
  const float* dw_f = (const float*)d_in[11];
  const float* lw = (const float*)d_in[12];
  float* out = (float*)d_out;  // f32 logits

  char* p = (char*)d_ws;
  float* x = (float*)p;        p += (size_t)2048 * 1024 * 4;  // f32 residual stream
  __bf16* h = (__bf16*)p;      p += (size_t)2048 * 1024 * 2;  // rmsnorm output
  __bf16* qb = (__bf16*)p;     p += (size_t)2048 * 1024 * 2;  // q proj
  __bf16* kvb = (__bf16*)p;    p += (size_t)2048 * 512 * 2;   // kv proj
  __bf16* ao = (__bf16*)p;     p += (size_t)2048 * 1024 * 2;  // attention out
  __bf16* gb = (__bf16*)p;     p += (size_t)2048 * 2816 * 2;  // gate (then swiglu result)
  __bf16* ub = (__bf16*)p;     p += (size_t)2048 * 2816 * 2;  // up
  __bf16* emb_b = (__bf16*)p;  p += (size_t)32000 * 1024 * 2; // bf16 embed for lm_head

  // convert embed to bf16 (used by the 16-pass lm_head GEMM)
  cvt_kernel<<<2048, 256, 0, stream>>>(emb_f, emb_b, 32000 * 1024 / 4);

  embed_kernel<<<2048, 256, 0, stream>>>(ids, emb_f, x);
  for (int l = 0; l < 4; ++l) {
    rmsnorm_kernel<<<2048, 256, 0, stream>>>(x, ln1 + l * 1024, h);
    gemm_bt<1, false, false><<<dim3(8, 16), 256, 0, stream>>>(
        h, qw_f + (size_t)l * 1024 * 1024, nullptr, q_b + l * 1024, qb, nullptr, 1024, 1024);
    gemm_bt<1, false, false><<<dim3(4, 16), 256, 0, stream>>>(
        h, kvw_f + (size_t)l * 512 * 1024, nullptr, kv_b + l * 512, kvb, nullptr, 1024, 512);
    rope_kernel<<<2048, 256, 0, stream>>>(qb, kvb);
    attn_kernel<<<dim3(8, 16, 4), 256, 0, stream>>>(qb, kvb, ao);
    gemm_bt<2, false, false><<<dim3(8, 16), 256, 0, stream>>>(
        ao, ow_f + (size_t)l * 1024 * 1024, nullptr, nullptr, nullptr, x, 1024, 1024);
    rmsnorm_kernel<<<2048, 256, 0, stream>>>(x, ln2 + l * 1024, h);
    gemm_bt<0, false, false><<<dim3(22, 16), 256, 0, stream>>>(
        h, gw_f + (size_t)l * 2816 * 1024, nullptr, nullptr, gb, nullptr, 1024, 2816);
    gemm_bt<0, false, false><<<dim3(22, 16), 256, 0, stream>>>(
        h, uw_f + (size_t)l * 2816 * 1024, nullptr, nullptr, ub, nullptr, 1024, 2816);
    const int nsw = 2048 * 2816;
    swiglu_kernel<<<(nsw + 255) / 256, 256, 0, stream>>>(gb, ub, nsw);
    gemm_bt<2, false, false><<<dim3(8, 16), 256, 0, stream>>>(
        gb, dw_f + (size_t)l * 1024 * 2816, nullptr, nullptr, nullptr, x, 2816, 1024);
  }
  rmsnorm_kernel<<<2048, 256, 0, stream>>>(x, lw, h);
  // lm_head: M=2048 (16 bm), N=32000 (250 bn), flat grid 4000 = 8*500, XCD-chunked, bm-inner
  gemm_bt<3, true, true><<<4000, 256, 0, stream>>>(
      h, nullptr, emb_b, nullptr, nullptr, out, 1024, 32000);
}

// Round 5
// 1603.782 us; speedup vs baseline: 1.1106x; 1.0684x over previous
//
#include <hip/hip_runtime.h>
#include <hip/hip_bf16.h>
#include <stdint.h>

// Model dims: L=4, D=1024, H=16, G=4, HS=64, I=2816, V=32000, B=4, T=512. NT = 2048.
// Inputs: f32 (+ int32 ids). Output: f32 logits [B,T,V].

typedef __bf16 bf16x8 __attribute__((ext_vector_type(8)));
typedef __bf16 bf16x4 __attribute__((ext_vector_type(4)));
typedef float  f32x4  __attribute__((ext_vector_type(4)));

#define AS1 __attribute__((address_space(1)))
#define AS3 __attribute__((address_space(3)))

__device__ __forceinline__ void gld_lds16(const void* g, void* l) {
  __builtin_amdgcn_global_load_lds((const AS1 void*)g, (AS3 void*)l, 16, 0, 0);
}

// ---------------- f32 -> bf16 convert (vectorized, grid-stride) ----------------
__global__ __launch_bounds__(256) void cvt_kernel(const float* __restrict__ in,
                                                  __bf16* __restrict__ out, int n4) {
  for (int i = blockIdx.x * 256 + threadIdx.x; i < n4; i += gridDim.x * 256) {
    f32x4 v = ((const f32x4*)in)[i];
    bf16x4 o;
#pragma unroll
    for (int j = 0; j < 4; ++j) o[j] = (__bf16)v[j];
    ((bf16x4*)out)[i] = o;
  }
}

// ---------------- embedding lookup ----------------
__global__ __launch_bounds__(256) void embed_kernel(const int* __restrict__ ids,
                                                    const float* __restrict__ emb,
                                                    float* __restrict__ x) {
  const int tok = blockIdx.x;
  const float* src = emb + (size_t)ids[tok] * 1024;
  float* dst = x + (size_t)tok * 1024;
#pragma unroll
  for (int j = 0; j < 4; ++j) {
    const int d = threadIdx.x + j * 256;
    dst[d] = src[d];
  }
}

// ---------------- RMSNorm ----------------
__global__ __launch_bounds__(256) void rmsnorm_kernel(const float* __restrict__ x,
                                                      const float* __restrict__ wgt,
                                                      __bf16* __restrict__ out) {
  const int row = blockIdx.x;
  const float* xr = x + (size_t)row * 1024;
  float v[4];
  float ss = 0.f;
#pragma unroll
  for (int j = 0; j < 4; ++j) { v[j] = xr[threadIdx.x + j * 256]; ss += v[j] * v[j]; }
#pragma unroll
  for (int m = 1; m < 64; m <<= 1) ss += __shfl_xor(ss, m, 64);
  __shared__ float red[4];
  if ((threadIdx.x & 63) == 0) red[threadIdx.x >> 6] = ss;
  __syncthreads();
  const float tot = red[0] + red[1] + red[2] + red[3];
  const float sc = rsqrtf(tot * (1.f / 1024.f) + 1e-6f);
#pragma unroll
  for (int j = 0; j < 4; ++j) {
    const int d = threadIdx.x + j * 256;
    out[(size_t)row * 1024 + d] = (__bf16)(v[j] * sc * wgt[d]);
  }
}

// ======== shared GEMM building blocks (128x128 tile, BK=32, 4 waves 2x2) ========
// A staging: bf16 global_load_lds. B staging: f32 load + cvt + ds_write.
// MFMA fragment read: A/B row = *16+lr, K-half lk. C/D: col=lane&15, row=(lane>>4)*4+reg.

#define GEMM_PREAMBLE                                              \
  const int t = threadIdx.x;                                       \
  const int lane = t & 63;                                         \
  const int w = t >> 6, wr = w >> 1, wc = w & 1;                   \
  const int lr = lane & 15;                                        \
  const int lk = (lane >> 4) * 8;                                  \
  const int sr = t >> 2;                                           \
  const int scol = (t & 3) * 8;                                    \
  const int br = t >> 3;                                           \
  const int bc = (t & 7) * 4;

#define STAGE_B_F32(bsrc, K)                                       \
  _Pragma("unroll") for (int j = 0; j < 4; ++j) {                  \
    f32x4 v = *(const f32x4*)((bsrc) + (size_t)(j * 32) * (K) + k0); \
    bf16x4 o;                                                      \
    _Pragma("unroll") for (int jj = 0; jj < 4; ++jj) o[jj] = (__bf16)v[jj]; \
    *(bf16x4*)&Bs[(br + j * 32) * 32 + bc] = o;                    \
  }

#define GEMM_FRAGS_MFMA                                            \
  bf16x8 af[4], bfr[4];                                            \
  _Pragma("unroll") for (int m = 0; m < 4; ++m)                    \
    af[m] = *(const bf16x8*)&As[(wr * 64 + m * 16 + lr) * 32 + lk];\
  _Pragma("unroll") for (int n = 0; n < 4; ++n)                    \
    bfr[n] = *(const bf16x8*)&Bs[(wc * 64 + n * 16 + lr) * 32 + lk];\
  _Pragma("unroll") for (int m = 0; m < 4; ++m)                    \
    _Pragma("unroll") for (int n = 0; n < 4; ++n)                  \
      acc[m][n] = __builtin_amdgcn_mfma_f32_16x16x32_bf16(af[m], bfr[n], acc[m][n], 0, 0, 0);

// ---------------- generic GEMM (o-proj accumulate, lm_head) ----------------
// EPI: 2 = accumulate into f32 C, 3 = store f32.  BB16: B bf16 via gld_lds.  SWZ: lm_head grid.
template <int EPI, bool BB16, bool SWZ>
__global__ __launch_bounds__(256) void gemm_bt(const __bf16* __restrict__ A,
                                               const float* __restrict__ Bw,
                                               const __bf16* __restrict__ Bb,
                                               float* __restrict__ Cf,
                                               int K, int ldc) {
  __shared__ __bf16 As[128 * 32];
  __shared__ __bf16 Bs[128 * 32];
  GEMM_PREAMBLE
  int bm, bn;
  if (SWZ) {
    const int bid = blockIdx.x;
    const int chunk = gridDim.x >> 3;  // grid % 8 == 0
    const int wg = (bid & 7) * chunk + (bid >> 3);
    bm = wg & 15;
    bn = wg >> 4;
  } else {
    bm = blockIdx.y;
    bn = blockIdx.x;
  }
  const __bf16* a0 = A + (size_t)(bm * 128 + sr) * K + scol;
  const __bf16* a1 = A + (size_t)(bm * 128 + 64 + sr) * K + scol;
  const float* bsrc = BB16 ? nullptr : (Bw + (size_t)(bn * 128 + br) * K + bc);
  const __bf16* bb0 = BB16 ? (Bb + (size_t)(bn * 128 + sr) * K + scol) : nullptr;
  const __bf16* bb1 = BB16 ? (Bb + (size_t)(bn * 128 + 64 + sr) * K + scol) : nullptr;

  f32x4 acc[4][4] = {};
  for (int k0 = 0; k0 < K; k0 += 32) {
    gld_lds16(a0 + k0, &As[t * 8]);
    gld_lds16(a1 + k0, &As[2048 + t * 8]);
    if (BB16) {
      gld_lds16(bb0 + k0, &Bs[t * 8]);
      gld_lds16(bb1 + k0, &Bs[2048 + t * 8]);
    } else {
      STAGE_B_F32(bsrc, K)
    }
    __syncthreads();
    GEMM_FRAGS_MFMA
    __syncthreads();
  }
  const int r0 = bm * 128 + wr * 64 + (lane >> 4) * 4;
  const int c0 = bn * 128 + wc * 64 + lr;
#pragma unroll
  for (int m = 0; m < 4; ++m)
#pragma unroll
    for (int r = 0; r < 4; ++r) {
      const size_t rowoff = (size_t)(r0 + m * 16 + r) * ldc;
#pragma unroll
      for (int n = 0; n < 4; ++n) {
        if (EPI == 2) Cf[rowoff + c0 + n * 16] += acc[m][n][r];
        else          Cf[rowoff + c0 + n * 16] = acc[m][n][r];
      }
    }
}

// ---------------- fused q+kv projection with bias + RoPE epilogue ----------------
// grid (12, 16): bn 0..7 -> q [2048,1024]; bn 8..11 -> kv [2048,512]; K=1024.
__global__ __launch_bounds__(256) void qkv_gemm(const __bf16* __restrict__ A,
                                                const float* __restrict__ qw,
                                                const float* __restrict__ kvw,
                                                const float* __restrict__ q_b,
                                                const float* __restrict__ kv_b,
                                                __bf16* __restrict__ qb,
                                                __bf16* __restrict__ kvb) {
  const int K = 1024;
  __shared__ __bf16 As[128 * 32];
  __shared__ __bf16 Bs[128 * 32];
  GEMM_PREAMBLE
  const int bm = blockIdx.y, bn = blockIdx.x;
  const bool isq = bn < 8;
  const int bnn = isq ? bn : bn - 8;
  const float* Bw = (isq ? qw : kvw) + (size_t)(bnn * 128) * K;

  const __bf16* a0 = A + (size_t)(bm * 128 + sr) * K + scol;
  const __bf16* a1 = A + (size_t)(bm * 128 + 64 + sr) * K + scol;
  const float* bsrc = Bw + (size_t)br * K + bc;

  f32x4 acc[4][4] = {};
  for (int k0 = 0; k0 < K; k0 += 32) {
    gld_lds16(a0 + k0, &As[t * 8]);
    gld_lds16(a1 + k0, &As[2048 + t * 8]);
    STAGE_B_F32(bsrc, K)
    __syncthreads();
    GEMM_FRAGS_MFMA
    __syncthreads();
  }

  const int ldc = isq ? 1024 : 512;
  __bf16* out = isq ? qb : kvb;
  const float* bias = isq ? q_b : kv_b;
  const int cb = bnn * 128 + wc * 64;  // head-aligned column base
  const bool dorope = isq || (cb < 256);  // q heads all roped; kv: only K region
  float bv[4];
#pragma unroll
  for (int n = 0; n < 4; ++n) bv[n] = bias[cb + n * 16 + lr];
  // RoPE inv freqs for this thread's two i values (i = n*16+lr, n=0,1)
  float inv0 = __expf((float)lr * -0.28782313662425574f);
  float inv1 = __expf((float)(16 + lr) * -0.28782313662425574f);

  const int r0 = bm * 128 + wr * 64 + (lane >> 4) * 4;
#pragma unroll
  for (int m = 0; m < 4; ++m)
#pragma unroll
    for (int r = 0; r < 4; ++r) {
      const int row = r0 + m * 16 + r;
      float c4[4];
#pragma unroll
      for (int n = 0; n < 4; ++n) c4[n] = acc[m][n][r] + bv[n];
      if (dorope) {
        const float pos = (float)(row & 511);
        float sg, cg;
        __sincosf(pos * inv0, &sg, &cg);
        float x1 = c4[0], x2 = c4[2];
        c4[0] = x1 * cg - x2 * sg;
        c4[2] = x2 * cg + x1 * sg;
        __sincosf(pos * inv1, &sg, &cg);
        x1 = c4[1]; x2 = c4[3];
        c4[1] = x1 * cg - x2 * sg;
        c4[3] = x2 * cg + x1 * sg;
      }
      const size_t rowoff = (size_t)row * ldc;
#pragma unroll
      for (int n = 0; n < 4; ++n) out[rowoff + cb + n * 16 + lr] = (__bf16)c4[n];
    }
}

// ---------------- fused gate+up projection ----------------
// grid (44, 16): bn 0..21 -> gate -> gb; bn 22..43 -> up -> ub. K=1024, ldc=2816.
__global__ __launch_bounds__(256) void gateup_gemm(const __bf16* __restrict__ A,
                                                   const float* __restrict__ gw,
                                                   const float* __restrict__ uw,
                                                   __bf16* __restrict__ gbuf,
                                                   __bf16* __restrict__ ubuf) {
  const int K = 1024;
  __shared__ __bf16 As[128 * 32];
  __shared__ __bf16 Bs[128 * 32];
  GEMM_PREAMBLE
  const int bm = blockIdx.y, bn = blockIdx.x;
  const bool isg = bn < 22;
  const int bnn = isg ? bn : bn - 22;
  const float* Bw = (isg ? gw : uw) + (size_t)(bnn * 128) * K;
  __bf16* out = isg ? gbuf : ubuf;

  const __bf16* a0 = A + (size_t)(bm * 128 + sr) * K + scol;
  const __bf16* a1 = A + (size_t)(bm * 128 + 64 + sr) * K + scol;
  const float* bsrc = Bw + (size_t)br * K + bc;

  f32x4 acc[4][4] = {};
  for (int k0 = 0; k0 < K; k0 += 32) {
    gld_lds16(a0 + k0, &As[t * 8]);
    gld_lds16(a1 + k0, &As[2048 + t * 8]);
    STAGE_B_F32(bsrc, K)
    __syncthreads();
    GEMM_FRAGS_MFMA
    __syncthreads();
  }
  const int r0 = bm * 128 + wr * 64 + (lane >> 4) * 4;
  const int c0 = bnn * 128 + wc * 64 + lr;
#pragma unroll
  for (int m = 0; m < 4; ++m)
#pragma unroll
    for (int r = 0; r < 4; ++r) {
      const size_t rowoff = (size_t)(r0 + m * 16 + r) * 2816;
#pragma unroll
      for (int n = 0; n < 4; ++n) out[rowoff + c0 + n * 16] = (__bf16)acc[m][n][r];
    }
}

// ---------------- down projection with fused SwiGLU A-staging ----------------
// A = silu(g)*u computed in-register during staging. K=2816, accumulate into f32 x.
__global__ __launch_bounds__(256) void down_gemm(const __bf16* __restrict__ g,
                                                 const __bf16* __restrict__ u,
                                                 const float* __restrict__ Bw,
                                                 float* __restrict__ Cf) {
  const int K = 2816;
  __shared__ __bf16 As[128 * 32];
  __shared__ __bf16 Bs[128 * 32];
  GEMM_PREAMBLE
  const int bm = blockIdx.y, bn = blockIdx.x;

  const size_t arow0 = (size_t)(bm * 128 + sr) * K + scol;
  const size_t arow1 = (size_t)(bm * 128 + 64 + sr) * K + scol;
  const float* bsrc = Bw + (size_t)(bn * 128 + br) * K + bc;

  f32x4 acc[4][4] = {};
  for (int k0 = 0; k0 < K; k0 += 32) {
    {
      bf16x8 gv0 = *(const bf16x8*)(g + arow0 + k0);
      bf16x8 uv0 = *(const bf16x8*)(u + arow0 + k0);
      bf16x8 gv1 = *(const bf16x8*)(g + arow1 + k0);
      bf16x8 uv1 = *(const bf16x8*)(u + arow1 + k0);
      bf16x8 s0, s1;
#pragma unroll
      for (int j = 0; j < 8; ++j) {
        const float gf = (float)gv0[j];
        s0[j] = (__bf16)(gf / (1.f + __expf(-gf)) * (float)uv0[j]);
      }
#pragma unroll
      for (int j = 0; j < 8; ++j) {
        const float gf = (float)gv1[j];
        s1[j] = (__bf16)(gf / (1.f + __expf(-gf)) * (float)uv1[j]);
      }
      *(bf16x8*)&As[t * 8] = s0;
      *(bf16x8*)&As[2048 + t * 8] = s1;
    }
    STAGE_B_F32(bsrc, K)
    __syncthreads();
    GEMM_FRAGS_MFMA
    __syncthreads();
  }
  const int r0 = bm * 128 + wr * 64 + (lane >> 4) * 4;
  const int c0 = bn * 128 + wc * 64 + lr;
#pragma unroll
  for (int m = 0; m < 4; ++m)
#pragma unroll
    for (int r = 0; r < 4; ++r) {
      const size_t rowoff = (size_t)(r0 + m * 16 + r) * 1024;
#pragma unroll
      for (int n = 0; n < 4; ++n) Cf[rowoff + c0 + n * 16] += acc[m][n][r];
    }
}

// ---------------- causal GQA flash attention ----------------
__global__ __launch_bounds__(256) void attn_kernel(const __bf16* __restrict__ q,
                                                   const __bf16* __restrict__ kv,
                                                   __bf16* __restrict__ o) {
  const int qt = blockIdx.x, hh = blockIdx.y, b = blockIdx.z;
  const int g = hh >> 2;
  const int t = threadIdx.x, lane = t & 63, w = t >> 6;
  const int lr = lane & 15, lg = lane >> 4;

  __shared__ __bf16 Ks[64 * 64];
  __shared__ __bf16 Vt[64 * 64];
  __shared__ __bf16 Ps[64 * 64];

  bf16x8 qa[2];
  {
    const size_t qoff = ((size_t)(b * 512 + qt * 64 + w * 16 + lr)) * 1024 + hh * 64;
    qa[0] = *(const bf16x8*)(q + qoff + lg * 8);
    qa[1] = *(const bf16x8*)(q + qoff + 32 + lg * 8);
  }

  f32x4 acc_o[4] = {};
  float mrow[4], lrow[4];
#pragma unroll
  for (int r = 0; r < 4; ++r) { mrow[r] = -1e30f; lrow[r] = 0.f; }

  const int srow = t >> 3;
  const int sd = (t & 7) * 8;

  for (int kt = 0; kt <= qt; ++kt) {
    const size_t krow = ((size_t)(b * 512 + kt * 64 + srow)) * 512;
    gld_lds16(kv + krow + g * 64 + sd, &Ks[t * 8]);
    gld_lds16(kv + krow + 32 * 512 + g * 64 + sd, &Ks[2048 + t * 8]);
    {
      const __bf16* vsrc = kv + krow + 256 + g * 64 + sd;
      bf16x8 v0 = *(const bf16x8*)vsrc;
      bf16x8 v1 = *(const bf16x8*)(vsrc + 32 * 512);
#pragma unroll
      for (int j = 0; j < 8; ++j) Vt[(sd + j) * 64 + srow] = v0[j];
#pragma unroll
      for (int j = 0; j < 8; ++j) Vt[(sd + j) * 64 + srow + 32] = v1[j];
    }
    __syncthreads();

    f32x4 s[4] = {};
#pragma unroll
    for (int nf = 0; nf < 4; ++nf)
#pragma unroll
      for (int kc = 0; kc < 2; ++kc) {
        bf16x8 kb = *(const bf16x8*)&Ks[(nf * 16 + lr) * 64 + kc * 32 + lg * 8];
        s[nf] = __builtin_amdgcn_mfma_f32_16x16x32_bf16(qa[kc], kb, s[nf], 0, 0, 0);
      }

    float pm[4][4], mx[4];
    const int qg = qt * 64 + w * 16 + lg * 4;
    const int kg = kt * 64 + lr;
#pragma unroll
    for (int r = 0; r < 4; ++r) mx[r] = -1e30f;
#pragma unroll
    for (int nf = 0; nf < 4; ++nf)
#pragma unroll
      for (int r = 0; r < 4; ++r) {
        float vv = s[nf][r] * 0.125f;
        vv = (kg + nf * 16 <= qg + r) ? vv : -1e30f;
        pm[nf][r] = vv;
        mx[r] = fmaxf(mx[r], vv);
      }
#pragma unroll
    for (int msk = 1; msk < 16; msk <<= 1)
#pragma unroll
      for (int r = 0; r < 4; ++r) mx[r] = fmaxf(mx[r], __shfl_xor(mx[r], msk, 64));

    float rs[4];
#pragma unroll
    for (int r = 0; r < 4; ++r) {
      const float mn = fmaxf(mrow[r], mx[r]);
      const float f = __expf(mrow[r] - mn);
      mrow[r] = mn;
      lrow[r] *= f;
#pragma unroll
      for (int df = 0; df < 4; ++df) acc_o[df][r] *= f;
      float rsum = 0.f;
#pragma unroll
      for (int nf = 0; nf < 4; ++nf) {
        const float pp = __expf(pm[nf][r] - mn);
        pm[nf][r] = pp;
        rsum += pp;
      }
      rs[r] = rsum;
    }
#pragma unroll
    for (int msk = 1; msk < 16; msk <<= 1)
#pragma unroll
      for (int r = 0; r < 4; ++r) rs[r] += __shfl_xor(rs[r], msk, 64);
#pragma unroll
    for (int r = 0; r < 4; ++r) lrow[r] += rs[r];

#pragma unroll
    for (int nf = 0; nf < 4; ++nf)
#pragma unroll
      for (int r = 0; r < 4; ++r)
        Ps[(w * 16 + lg * 4 + r) * 64 + nf * 16 + lr] = (__bf16)pm[nf][r];

#pragma unroll
    for (int df = 0; df < 4; ++df)
#pragma unroll
      for (int kc = 0; kc < 2; ++kc) {
        bf16x8 pa = *(const bf16x8*)&Ps[(w * 16 + lr) * 64 + kc * 32 + lg * 8];
        bf16x8 vb = *(const bf16x8*)&Vt[(df * 16 + lr) * 64 + kc * 32 + lg * 8];
        acc_o[df] = __builtin_amdgcn_mfma_f32_16x16x32_bf16(pa, vb, acc_o[df], 0, 0, 0);
      }
    __syncthreads();
  }

#pragma unroll
  for (int df = 0; df < 4; ++df)
#pragma unroll
    for (int r = 0; r < 4; ++r) {
      const int trow = qt * 64 + w * 16 + lg * 4 + r;
      o[((size_t)(b * 512 + trow)) * 1024 + hh * 64 + df * 16 + lr] =
          (__bf16)(acc_o[df][r] / lrow[r]);
    }
}

extern "C" void kernel_launch(void* const* d_in, const int* in_sizes, int n_in,
                              void* d_out, int out_size, void* d_ws, size_t ws_size,
                              hipStream_t stream) {
  const int* ids = (const int*)d_in[0];
  const float* emb_f = (const float*)d_in[1];
  const float* qw_f = (const float*)d_in[2];
  const float* q_b = (const float*)d_in[3];
  const float* kvw_f = (const float*)d_in[4];
  const float* kv_b = (const float*)d_in[5];
  const float* ow_f = (const float*)d_in[6];
  const float* ln1 = (const float*)d_in[7];
  const float* ln2 = (const float*)d_in[8];
  const float* gw_f = (const float*)d_in[9];
  const float* uw_f = (const float*)d_in[10];
  const float* dw_f = (const float*)d_in[11];
  const float* lw = (const float*)d_in[12];
  float* out = (float*)d_out;  // f32 logits

  char* p = (char*)d_ws;
  float* x = (float*)p;        p += (size_t)2048 * 1024 * 4;
  __bf16* h = (__bf16*)p;      p += (size_t)2048 * 1024 * 2;
  __bf16* qb = (__bf16*)p;     p += (size_t)2048 * 1024 * 2;
  __bf16* kvb = (__bf16*)p;    p += (size_t)2048 * 512 * 2;
  __bf16* ao = (__bf16*)p;     p += (size_t)2048 * 1024 * 2;
  __bf16* gb = (__bf16*)p;     p += (size_t)2048 * 2816 * 2;
  __bf16* ub = (__bf16*)p;     p += (size_t)2048 * 2816 * 2;
  __bf16* emb_b = (__bf16*)p;  p += (size_t)32000 * 1024 * 2;

  cvt_kernel<<<2048, 256, 0, stream>>>(emb_f, emb_b, 32000 * 1024 / 4);
  embed_kernel<<<2048, 256, 0, stream>>>(ids, emb_f, x);
  for (int l = 0; l < 4; ++l) {
    rmsnorm_kernel<<<2048, 256, 0, stream>>>(x, ln1 + l * 1024, h);
    qkv_gemm<<<dim3(12, 16), 256, 0, stream>>>(
        h, qw_f + (size_t)l * 1024 * 1024, kvw_f + (size_t)l * 512 * 1024,
        q_b + l * 1024, kv_b + l * 512, qb, kvb);
    attn_kernel<<<dim3(8, 16, 4), 256, 0, stream>>>(qb, kvb, ao);
    gemm_bt<2, false, false><<<dim3(8, 16), 256, 0, stream>>>(
        ao, ow_f + (size_t)l * 1024 * 1024, nullptr, x, 1024, 1024);
    rmsnorm_kernel<<<2048, 256, 0, stream>>>(x, ln2 + l * 1024, h);
    gateup_gemm<<<dim3(44, 16), 256, 0, stream>>>(
        h, gw_f + (size_t)l * 2816 * 1024, uw_f + (size_t)l * 2816 * 1024, gb, ub);
    down_gemm<<<dim3(8, 16), 256, 0, stream>>>(
        gb, ub, dw_f + (size_t)l * 1024 * 2816, x);
  }
  rmsnorm_kernel<<<2048, 256, 0, stream>>>(x, lw, h);
  gemm_bt<3, true, true><<<4000, 256, 0, stream>>>(
      h, nullptr, emb_b, out, 1024, 32000);
}

// Round 6
// 1140.759 us; speedup vs baseline: 1.5614x; 1.4059x over previous
//
#include <hip/hip_runtime.h>
#include <hip/hip_bf16.h>
#include <stdint.h>

// Model dims: L=4, D=1024, H=16, G=4, HS=64, I=2816, V=32000, B=4, T=512. NT = 2048.
// Inputs: f32 (+ int32 ids). Output: f32 logits [B,T,V].

typedef __bf16 bf16x8 __attribute__((ext_vector_type(8)));
typedef __bf16 bf16x4 __attribute__((ext_vector_type(4)));
typedef float  f32x4  __attribute__((ext_vector_type(4)));

#define AS1 __attribute__((address_space(1)))
#define AS3 __attribute__((address_space(3)))

__device__ __forceinline__ void gld_lds16(const void* g, void* l) {
  __builtin_amdgcn_global_load_lds((const AS1 void*)g, (AS3 void*)l, 16, 0, 0);
}

// ---------------- f32 -> bf16 convert (vectorized, grid-stride) ----------------
__global__ __launch_bounds__(256) void cvt_kernel(const float* __restrict__ in,
                                                  __bf16* __restrict__ out, int n4) {
  for (int i = blockIdx.x * 256 + threadIdx.x; i < n4; i += gridDim.x * 256) {
    f32x4 v = ((const f32x4*)in)[i];
    bf16x4 o;
#pragma unroll
    for (int j = 0; j < 4; ++j) o[j] = (__bf16)v[j];
    ((bf16x4*)out)[i] = o;
  }
}

// ---------------- embedding lookup ----------------
__global__ __launch_bounds__(256) void embed_kernel(const int* __restrict__ ids,
                                                    const float* __restrict__ emb,
                                                    float* __restrict__ x) {
  const int tok = blockIdx.x;
  const float* src = emb + (size_t)ids[tok] * 1024;
  float* dst = x + (size_t)tok * 1024;
#pragma unroll
  for (int j = 0; j < 4; ++j) {
    const int d = threadIdx.x + j * 256;
    dst[d] = src[d];
  }
}

// ---------------- RMSNorm ----------------
__global__ __launch_bounds__(256) void rmsnorm_kernel(const float* __restrict__ x,
                                                      const float* __restrict__ wgt,
                                                      __bf16* __restrict__ out) {
  const int row = blockIdx.x;
  const float* xr = x + (size_t)row * 1024;
  float v[4];
  float ss = 0.f;
#pragma unroll
  for (int j = 0; j < 4; ++j) { v[j] = xr[threadIdx.x + j * 256]; ss += v[j] * v[j]; }
#pragma unroll
  for (int m = 1; m < 64; m <<= 1) ss += __shfl_xor(ss, m, 64);
  __shared__ float red[4];
  if ((threadIdx.x & 63) == 0) red[threadIdx.x >> 6] = ss;
  __syncthreads();
  const float tot = red[0] + red[1] + red[2] + red[3];
  const float sc = rsqrtf(tot * (1.f / 1024.f) + 1e-6f);
#pragma unroll
  for (int j = 0; j < 4; ++j) {
    const int d = threadIdx.x + j * 256;
    out[(size_t)row * 1024 + d] = (__bf16)(v[j] * sc * wgt[d]);
  }
}

// ======== shared GEMM building blocks (128x128 tile, BK=32, 4 waves 2x2, bf16 B) ========
#define GEMM_PREAMBLE                                              \
  const int t = threadIdx.x;                                       \
  const int lane = t & 63;                                         \
  const int w = t >> 6, wr = w >> 1, wc = w & 1;                   \
  const int lr = lane & 15;                                        \
  const int lk = (lane >> 4) * 8;                                  \
  const int sr = t >> 2;                                           \
  const int scol = (t & 3) * 8;

// flat grid, XCD-chunked (grid % 8 == 0), bm-inner decomposition
#define FLAT_SWZ(BMC, BNC)                                         \
  const int chunk_ = (int)(gridDim.x >> 3);                        \
  const int wg_ = (blockIdx.x & 7) * chunk_ + (blockIdx.x >> 3);   \
  const int bm = wg_ % (BMC);                                      \
  const int rest_ = wg_ / (BMC);                                   \
  const int bn = rest_ % (BNC);                                    \
  const int ks = rest_ / (BNC);                                    \
  (void)ks;

#define GEMM_FRAGS_MFMA                                            \
  bf16x8 af[4], bfr[4];                                            \
  _Pragma("unroll") for (int m = 0; m < 4; ++m)                    \
    af[m] = *(const bf16x8*)&As[(wr * 64 + m * 16 + lr) * 32 + lk];\
  _Pragma("unroll") for (int n = 0; n < 4; ++n)                    \
    bfr[n] = *(const bf16x8*)&Bs[(wc * 64 + n * 16 + lr) * 32 + lk];\
  _Pragma("unroll") for (int m = 0; m < 4; ++m)                    \
    _Pragma("unroll") for (int n = 0; n < 4; ++n)                  \
      acc[m][n] = __builtin_amdgcn_mfma_f32_16x16x32_bf16(af[m], bfr[n], acc[m][n], 0, 0, 0);

// ---------------- generic GEMM, bf16 A and B, flat swizzled grid ----------------
// EPI: 3 = store f32, 4 = atomicAdd f32 (split-K). Grid = BMC*BNC*KSP (%8==0).
template <int EPI, int BMC, int BNC, int KSP>
__global__ __launch_bounds__(256) void gemm_bt(const __bf16* __restrict__ A,
                                               const __bf16* __restrict__ Bb,
                                               float* __restrict__ Cf,
                                               int K, int ldc) {
  __shared__ __bf16 As[128 * 32];
  __shared__ __bf16 Bs[128 * 32];
  GEMM_PREAMBLE
  FLAT_SWZ(BMC, BNC)
  const int klen = K / KSP;
  const int kbeg = ks * klen;

  const __bf16* a0 = A + (size_t)(bm * 128 + sr) * K + scol;
  const __bf16* a1 = A + (size_t)(bm * 128 + 64 + sr) * K + scol;
  const __bf16* bb0 = Bb + (size_t)(bn * 128 + sr) * K + scol;
  const __bf16* bb1 = Bb + (size_t)(bn * 128 + 64 + sr) * K + scol;

  f32x4 acc[4][4] = {};
  for (int k0 = kbeg; k0 < kbeg + klen; k0 += 32) {
    gld_lds16(a0 + k0, &As[t * 8]);
    gld_lds16(a1 + k0, &As[2048 + t * 8]);
    gld_lds16(bb0 + k0, &Bs[t * 8]);
    gld_lds16(bb1 + k0, &Bs[2048 + t * 8]);
    __syncthreads();
    GEMM_FRAGS_MFMA
    __syncthreads();
  }
  const int r0 = bm * 128 + wr * 64 + (lane >> 4) * 4;
  const int c0 = bn * 128 + wc * 64 + lr;
#pragma unroll
  for (int m = 0; m < 4; ++m)
#pragma unroll
    for (int r = 0; r < 4; ++r) {
      const size_t rowoff = (size_t)(r0 + m * 16 + r) * ldc;
#pragma unroll
      for (int n = 0; n < 4; ++n) {
        if (EPI == 3) Cf[rowoff + c0 + n * 16] = acc[m][n][r];
        else          atomicAdd(&Cf[rowoff + c0 + n * 16], acc[m][n][r]);
      }
    }
}

// ---------------- fused q+kv projection (bf16 B) with bias + RoPE epilogue ----------------
// flat grid 192: bn 0..7 -> q [2048,1024]; bn 8..11 -> kv [2048,512]; K=1024.
__global__ __launch_bounds__(256) void qkv_gemm(const __bf16* __restrict__ A,
                                                const __bf16* __restrict__ qw,
                                                const __bf16* __restrict__ kvw,
                                                const float* __restrict__ q_b,
                                                const float* __restrict__ kv_b,
                                                __bf16* __restrict__ qb,
                                                __bf16* __restrict__ kvb) {
  const int K = 1024;
  __shared__ __bf16 As[128 * 32];
  __shared__ __bf16 Bs[128 * 32];
  GEMM_PREAMBLE
  FLAT_SWZ(16, 12)
  const bool isq = bn < 8;
  const int bnn = isq ? bn : bn - 8;
  const __bf16* Bw = (isq ? qw : kvw) + (size_t)(bnn * 128) * K;

  const __bf16* a0 = A + (size_t)(bm * 128 + sr) * K + scol;
  const __bf16* a1 = A + (size_t)(bm * 128 + 64 + sr) * K + scol;
  const __bf16* bb0 = Bw + (size_t)sr * K + scol;
  const __bf16* bb1 = Bw + (size_t)(64 + sr) * K + scol;

  f32x4 acc[4][4] = {};
  for (int k0 = 0; k0 < K; k0 += 32) {
    gld_lds16(a0 + k0, &As[t * 8]);
    gld_lds16(a1 + k0, &As[2048 + t * 8]);
    gld_lds16(bb0 + k0, &Bs[t * 8]);
    gld_lds16(bb1 + k0, &Bs[2048 + t * 8]);
    __syncthreads();
    GEMM_FRAGS_MFMA
    __syncthreads();
  }

  const int ldc = isq ? 1024 : 512;
  __bf16* out = isq ? qb : kvb;
  const float* bias = isq ? q_b : kv_b;
  const int cb = bnn * 128 + wc * 64;     // head-aligned column base
  const bool dorope = isq || (cb < 256);  // q heads all roped; kv: only K region
  float bv[4];
#pragma unroll
  for (int n = 0; n < 4; ++n) bv[n] = bias[cb + n * 16 + lr];
  float inv0 = __expf((float)lr * -0.28782313662425574f);
  float inv1 = __expf((float)(16 + lr) * -0.28782313662425574f);

  const int r0 = bm * 128 + wr * 64 + (lane >> 4) * 4;
#pragma unroll
  for (int m = 0; m < 4; ++m)
#pragma unroll
    for (int r = 0; r < 4; ++r) {
      const int row = r0 + m * 16 + r;
      float c4[4];
#pragma unroll
      for (int n = 0; n < 4; ++n) c4[n] = acc[m][n][r] + bv[n];
      if (dorope) {
        const float pos = (float)(row & 511);
        float sg, cg;
        __sincosf(pos * inv0, &sg, &cg);
        float x1 = c4[0], x2 = c4[2];
        c4[0] = x1 * cg - x2 * sg;
        c4[2] = x2 * cg + x1 * sg;
        __sincosf(pos * inv1, &sg, &cg);
        x1 = c4[1]; x2 = c4[3];
        c4[1] = x1 * cg - x2 * sg;
        c4[3] = x2 * cg + x1 * sg;
      }
      const size_t rowoff = (size_t)row * ldc;
#pragma unroll
      for (int n = 0; n < 4; ++n) out[rowoff + cb + n * 16 + lr] = (__bf16)c4[n];
    }
}

// ---------------- fused gate+up projection (bf16 B) ----------------
// flat grid 704: bn 0..21 -> gate; bn 22..43 -> up. K=1024, ldc=2816.
__global__ __launch_bounds__(256) void gateup_gemm(const __bf16* __restrict__ A,
                                                   const __bf16* __restrict__ gw,
                                                   const __bf16* __restrict__ uw,
                                                   __bf16* __restrict__ gbuf,
                                                   __bf16* __restrict__ ubuf) {
  const int K = 1024;
  __shared__ __bf16 As[128 * 32];
  __shared__ __bf16 Bs[128 * 32];
  GEMM_PREAMBLE
  FLAT_SWZ(16, 44)
  const bool isg = bn < 22;
  const int bnn = isg ? bn : bn - 22;
  const __bf16* Bw = (isg ? gw : uw) + (size_t)(bnn * 128) * K;
  __bf16* out = isg ? gbuf : ubuf;

  const __bf16* a0 = A + (size_t)(bm * 128 + sr) * K + scol;
  const __bf16* a1 = A + (size_t)(bm * 128 + 64 + sr) * K + scol;
  const __bf16* bb0 = Bw + (size_t)sr * K + scol;
  const __bf16* bb1 = Bw + (size_t)(64 + sr) * K + scol;

  f32x4 acc[4][4] = {};
  for (int k0 = 0; k0 < K; k0 += 32) {
    gld_lds16(a0 + k0, &As[t * 8]);
    gld_lds16(a1 + k0, &As[2048 + t * 8]);
    gld_lds16(bb0 + k0, &Bs[t * 8]);
    gld_lds16(bb1 + k0, &Bs[2048 + t * 8]);
    __syncthreads();
    GEMM_FRAGS_MFMA
    __syncthreads();
  }
  const int r0 = bm * 128 + wr * 64 + (lane >> 4) * 4;
  const int c0 = bnn * 128 + wc * 64 + lr;
#pragma unroll
  for (int m = 0; m < 4; ++m)
#pragma unroll
    for (int r = 0; r < 4; ++r) {
      const size_t rowoff = (size_t)(r0 + m * 16 + r) * 2816;
#pragma unroll
      for (int n = 0; n < 4; ++n) out[rowoff + c0 + n * 16] = (__bf16)acc[m][n][r];
    }
}

// ---------------- down projection: fused SwiGLU A-staging, bf16 B, split-K x2 ----------------
// flat grid 256: bm 16, bn 8, ks 2. K=2816 -> klen 1408. atomicAdd into f32 x.
__global__ __launch_bounds__(256) void down_gemm(const __bf16* __restrict__ g,
                                                 const __bf16* __restrict__ u,
                                                 const __bf16* __restrict__ Bb,
                                                 float* __restrict__ Cf) {
  const int K = 2816;
  __shared__ __bf16 As[128 * 32];
  __shared__ __bf16 Bs[128 * 32];
  GEMM_PREAMBLE
  FLAT_SWZ(16, 8)
  const int klen = 1408;
  const int kbeg = ks * klen;

  const size_t arow0 = (size_t)(bm * 128 + sr) * K + scol;
  const size_t arow1 = (size_t)(bm * 128 + 64 + sr) * K + scol;
  const __bf16* bb0 = Bb + (size_t)(bn * 128 + sr) * K + scol;
  const __bf16* bb1 = Bb + (size_t)(bn * 128 + 64 + sr) * K + scol;

  f32x4 acc[4][4] = {};
  for (int k0 = kbeg; k0 < kbeg + klen; k0 += 32) {
    {
      bf16x8 gv0 = *(const bf16x8*)(g + arow0 + k0);
      bf16x8 uv0 = *(const bf16x8*)(u + arow0 + k0);
      bf16x8 gv1 = *(const bf16x8*)(g + arow1 + k0);
      bf16x8 uv1 = *(const bf16x8*)(u + arow1 + k0);
      bf16x8 s0, s1;
#pragma unroll
      for (int j = 0; j < 8; ++j) {
        const float gf = (float)gv0[j];
        s0[j] = (__bf16)(gf / (1.f + __expf(-gf)) * (float)uv0[j]);
      }
#pragma unroll
      for (int j = 0; j < 8; ++j) {
        const float gf = (float)gv1[j];
        s1[j] = (__bf16)(gf / (1.f + __expf(-gf)) * (float)uv1[j]);
      }
      *(bf16x8*)&As[t * 8] = s0;
      *(bf16x8*)&As[2048 + t * 8] = s1;
    }
    gld_lds16(bb0 + k0, &Bs[t * 8]);
    gld_lds16(bb1 + k0, &Bs[2048 + t * 8]);
    __syncthreads();
    GEMM_FRAGS_MFMA
    __syncthreads();
  }
  const int r0 = bm * 128 + wr * 64 + (lane >> 4) * 4;
  const int c0 = bn * 128 + wc * 64 + lr;
#pragma unroll
  for (int m = 0; m < 4; ++m)
#pragma unroll
    for (int r = 0; r < 4; ++r) {
      const size_t rowoff = (size_t)(r0 + m * 16 + r) * 1024;
#pragma unroll
      for (int n = 0; n < 4; ++n) atomicAdd(&Cf[rowoff + c0 + n * 16], acc[m][n][r]);
    }
}

// ---------------- causal GQA flash attention ----------------
// K-tile: linear LDS via gld_lds with pre-swizzled source (chunk ^= row&7); read with same XOR.
// Vt/Ps: padded stride 72 (=9*16B, keeps b128 alignment; conflict-free transpose writes).
__global__ __launch_bounds__(256) void attn_kernel(const __bf16* __restrict__ q,
                                                   const __bf16* __restrict__ kv,
                                                   __bf16* __restrict__ o) {
  const int qt = blockIdx.x, hh = blockIdx.y, b = blockIdx.z;
  const int g = hh >> 2;
  const int t = threadIdx.x, lane = t & 63, w = t >> 6;
  const int lr = lane & 15, lg = lane >> 4;

  __shared__ __bf16 Ks[64 * 64];
  __shared__ __bf16 Vt[64 * 72];
  __shared__ __bf16 Ps[64 * 72];

  bf16x8 qa[2];
  {
    const size_t qoff = ((size_t)(b * 512 + qt * 64 + w * 16 + lr)) * 1024 + hh * 64;
    qa[0] = *(const bf16x8*)(q + qoff + lg * 8);
    qa[1] = *(const bf16x8*)(q + qoff + 32 + lg * 8);
  }

  f32x4 acc_o[4] = {};
  float mrow[4], lrow[4];
#pragma unroll
  for (int r = 0; r < 4; ++r) { mrow[r] = -1e30f; lrow[r] = 0.f; }

  const int srow = t >> 3;                              // staging row 0..31
  const int sd = (((t & 7) ^ (srow & 7)) * 8);          // XOR-swizzled chunk (K and V)

  for (int kt = 0; kt <= qt; ++kt) {
    const size_t krow = ((size_t)(b * 512 + kt * 64 + srow)) * 512;
    gld_lds16(kv + krow + g * 64 + sd, &Ks[t * 8]);
    gld_lds16(kv + krow + 32 * 512 + g * 64 + sd, &Ks[2048 + t * 8]);
    {
      const __bf16* vsrc = kv + krow + 256 + g * 64 + sd;
      bf16x8 v0 = *(const bf16x8*)vsrc;
      bf16x8 v1 = *(const bf16x8*)(vsrc + 32 * 512);
#pragma unroll
      for (int j = 0; j < 8; ++j) Vt[(sd + j) * 72 + srow] = v0[j];
#pragma unroll
      for (int j = 0; j < 8; ++j) Vt[(sd + j) * 72 + srow + 32] = v1[j];
    }
    __syncthreads();

    // S = Q K^T; K-frag read with matching XOR swizzle
    f32x4 s[4] = {};
#pragma unroll
    for (int nf = 0; nf < 4; ++nf)
#pragma unroll
      for (int kc = 0; kc < 2; ++kc) {
        bf16x8 kb = *(const bf16x8*)&Ks[(nf * 16 + lr) * 64 + (((kc * 4 + lg) ^ (lr & 7)) * 8)];
        s[nf] = __builtin_amdgcn_mfma_f32_16x16x32_bf16(qa[kc], kb, s[nf], 0, 0, 0);
      }

    float pm[4][4], mx[4];
    const int qg = qt * 64 + w * 16 + lg * 4;
    const int kg = kt * 64 + lr;
#pragma unroll
    for (int r = 0; r < 4; ++r) mx[r] = -1e30f;
#pragma unroll
    for (int nf = 0; nf < 4; ++nf)
#pragma unroll
      for (int r = 0; r < 4; ++r) {
        float vv = s[nf][r] * 0.125f;
        vv = (kg + nf * 16 <= qg + r) ? vv : -1e30f;
        pm[nf][r] = vv;
        mx[r] = fmaxf(mx[r], vv);
      }
#pragma unroll
    for (int msk = 1; msk < 16; msk <<= 1)
#pragma unroll
      for (int r = 0; r < 4; ++r) mx[r] = fmaxf(mx[r], __shfl_xor(mx[r], msk, 64));

    float rs[4];
#pragma unroll
    for (int r = 0; r < 4; ++r) {
      const float mn = fmaxf(mrow[r], mx[r]);
      const float f = __expf(mrow[r] - mn);
      mrow[r] = mn;
      lrow[r] *= f;
#pragma unroll
      for (int df = 0; df < 4; ++df) acc_o[df][r] *= f;
      float rsum = 0.f;
#pragma unroll
      for (int nf = 0; nf < 4; ++nf) {
        const float pp = __expf(pm[nf][r] - mn);
        pm[nf][r] = pp;
        rsum += pp;
      }
      rs[r] = rsum;
    }
#pragma unroll
    for (int msk = 1; msk < 16; msk <<= 1)
#pragma unroll
      for (int r = 0; r < 4; ++r) rs[r] += __shfl_xor(rs[r], msk, 64);
#pragma unroll
    for (int r = 0; r < 4; ++r) lrow[r] += rs[r];

    // P -> LDS (C-layout -> A-layout round trip), padded stride
#pragma unroll
    for (int nf = 0; nf < 4; ++nf)
#pragma unroll
      for (int r = 0; r < 4; ++r)
        Ps[(w * 16 + lg * 4 + r) * 72 + nf * 16 + lr] = (__bf16)pm[nf][r];

    // O += P V
#pragma unroll
    for (int df = 0; df < 4; ++df)
#pragma unroll
      for (int kc = 0; kc < 2; ++kc) {
        bf16x8 pa = *(const bf16x8*)&Ps[(w * 16 + lr) * 72 + kc * 32 + lg * 8];
        bf16x8 vb = *(const bf16x8*)&Vt[(df * 16 + lr) * 72 + kc * 32 + lg * 8];
        acc_o[df] = __builtin_amdgcn_mfma_f32_16x16x32_bf16(pa, vb, acc_o[df], 0, 0, 0);
      }
    __syncthreads();
  }

#pragma unroll
  for (int df = 0; df < 4; ++df)
#pragma unroll
    for (int r = 0; r < 4; ++r) {
      const int trow = qt * 64 + w * 16 + lg * 4 + r;
      o[((size_t)(b * 512 + trow)) * 1024 + hh * 64 + df * 16 + lr] =
          (__bf16)(acc_o[df][r] / lrow[r]);
    }
}

extern "C" void kernel_launch(void* const* d_in, const int* in_sizes, int n_in,
                              void* d_out, int out_size, void* d_ws, size_t ws_size,
                              hipStream_t stream) {
  const int* ids = (const int*)d_in[0];
  const float* emb_f = (const float*)d_in[1];
  const float* qw_f = (const float*)d_in[2];
  const float* q_b = (const float*)d_in[3];
  const float* kvw_f = (const float*)d_in[4];
  const float* kv_b = (const float*)d_in[5];
  const float* ow_f = (const float*)d_in[6];
  const float* ln1 = (const float*)d_in[7];
  const float* ln2 = (const float*)d_in[8];
  const float* gw_f = (const float*)d_in[9];
  const float* uw_f = (const float*)d_in[10];
  const float* dw_f = (const float*)d_in[11];
  const float* lw = (const float*)d_in[12];
  float* out = (float*)d_out;  // f32 logits

  char* p = (char*)d_ws;
  float* x = (float*)p;        p += (size_t)2048 * 1024 * 4;
  __bf16* h = (__bf16*)p;      p += (size_t)2048 * 1024 * 2;
  __bf16* qb = (__bf16*)p;     p += (size_t)2048 * 1024 * 2;
  __bf16* kvb = (__bf16*)p;    p += (size_t)2048 * 512 * 2;
  __bf16* ao = (__bf16*)p;     p += (size_t)2048 * 1024 * 2;
  __bf16* gb = (__bf16*)p;     p += (size_t)2048 * 2816 * 2;
  __bf16* ub = (__bf16*)p;     p += (size_t)2048 * 2816 * 2;
  __bf16* emb_b = (__bf16*)p;  p += (size_t)32000 * 1024 * 2;
  __bf16* qw_b = (__bf16*)p;   p += (size_t)4 * 1024 * 1024 * 2;
  __bf16* kvw_b = (__bf16*)p;  p += (size_t)4 * 512 * 1024 * 2;
  __bf16* ow_b = (__bf16*)p;   p += (size_t)4 * 1024 * 1024 * 2;
  __bf16* gw_b = (__bf16*)p;   p += (size_t)4 * 2816 * 1024 * 2;
  __bf16* uw_b = (__bf16*)p;   p += (size_t)4 * 2816 * 1024 * 2;
  __bf16* dw_b = (__bf16*)p;   p += (size_t)4 * 2816 * 1024 * 2;

  // one-time (per call) f32 -> bf16 weight conversion
  cvt_kernel<<<2048, 256, 0, stream>>>(emb_f, emb_b, 32000 * 1024 / 4);
  cvt_kernel<<<1024, 256, 0, stream>>>(qw_f, qw_b, 4 * 1024 * 1024 / 4);
  cvt_kernel<<<1024, 256, 0, stream>>>(kvw_f, kvw_b, 4 * 512 * 1024 / 4);
  cvt_kernel<<<1024, 256, 0, stream>>>(ow_f, ow_b, 4 * 1024 * 1024 / 4);
  cvt_kernel<<<1024, 256, 0, stream>>>(gw_f, gw_b, 4 * 2816 * 1024 / 4);
  cvt_kernel<<<1024, 256, 0, stream>>>(uw_f, uw_b, 4 * 2816 * 1024 / 4);
  cvt_kernel<<<1024, 256, 0, stream>>>(dw_f, dw_b, 4 * 2816 * 1024 / 4);

  embed_kernel<<<2048, 256, 0, stream>>>(ids, emb_f, x);
  for (int l = 0; l < 4; ++l) {
    rmsnorm_kernel<<<2048, 256, 0, stream>>>(x, ln1 + l * 1024, h);
    qkv_gemm<<<192, 256, 0, stream>>>(
        h, qw_b + (size_t)l * 1024 * 1024, kvw_b + (size_t)l * 512 * 1024,
        q_b + l * 1024, kv_b + l * 512, qb, kvb);
    attn_kernel<<<dim3(8, 16, 4), 256, 0, stream>>>(qb, kvb, ao);
    gemm_bt<4, 16, 8, 2><<<256, 256, 0, stream>>>(
        ao, ow_b + (size_t)l * 1024 * 1024, x, 1024, 1024);
    rmsnorm_kernel<<<2048, 256, 0, stream>>>(x, ln2 + l * 1024, h);
    gateup_gemm<<<704, 256, 0, stream>>>(
        h, gw_b + (size_t)l * 2816 * 1024, uw_b + (size_t)l * 2816 * 1024, gb, ub);
    down_gemm<<<256, 256, 0, stream>>>(
        gb, ub, dw_b + (size_t)l * 1024 * 2816, x);
  }
  rmsnorm_kernel<<<2048, 256, 0, stream>>>(x, lw, h);
  gemm_bt<3, 16, 250, 1><<<4000, 256, 0, stream>>>(h, emb_b, out, 1024, 32000);
}

// Round 7
// 1064.254 us; speedup vs baseline: 1.6736x; 1.0719x over previous
//
#include <hip/hip_runtime.h>
#include <hip/hip_bf16.h>
#include <stdint.h>

// Model dims: L=4, D=1024, H=16, G=4, HS=64, I=2816, V=32000, B=4, T=512. NT = 2048.
// Inputs: f32 (+ int32 ids). Output: f32 logits [B,T,V].

typedef __bf16 bf16x8 __attribute__((ext_vector_type(8)));
typedef __bf16 bf16x4 __attribute__((ext_vector_type(4)));
typedef float  f32x4  __attribute__((ext_vector_type(4)));

#define AS1 __attribute__((address_space(1)))
#define AS3 __attribute__((address_space(3)))

__device__ __forceinline__ void gld_lds16(const void* g, void* l) {
  __builtin_amdgcn_global_load_lds((const AS1 void*)g, (AS3 void*)l, 16, 0, 0);
}

// ---------------- f32 -> bf16 convert (vectorized, grid-stride, nt loads) ----------------
__global__ __launch_bounds__(256) void cvt_kernel(const float* __restrict__ in,
                                                  __bf16* __restrict__ out, int n4) {
  for (int i = blockIdx.x * 256 + threadIdx.x; i < n4; i += gridDim.x * 256) {
    f32x4 v = __builtin_nontemporal_load(&((const f32x4*)in)[i]);
    bf16x4 o;
#pragma unroll
    for (int j = 0; j < 4; ++j) o[j] = (__bf16)v[j];
    ((bf16x4*)out)[i] = o;
  }
}

// ---------------- embedding lookup ----------------
__global__ __launch_bounds__(256) void embed_kernel(const int* __restrict__ ids,
                                                    const float* __restrict__ emb,
                                                    float* __restrict__ x) {
  const int tok = blockIdx.x;
  const float* src = emb + (size_t)ids[tok] * 1024;
  float* dst = x + (size_t)tok * 1024;
#pragma unroll
  for (int j = 0; j < 4; ++j) {
    const int d = threadIdx.x + j * 256;
    dst[d] = src[d];
  }
}

// ---------------- RMSNorm ----------------
__global__ __launch_bounds__(256) void rmsnorm_kernel(const float* __restrict__ x,
                                                      const float* __restrict__ wgt,
                                                      __bf16* __restrict__ out) {
  const int row = blockIdx.x;
  const float* xr = x + (size_t)row * 1024;
  float v[4];
  float ss = 0.f;
#pragma unroll
  for (int j = 0; j < 4; ++j) { v[j] = xr[threadIdx.x + j * 256]; ss += v[j] * v[j]; }
#pragma unroll
  for (int m = 1; m < 64; m <<= 1) ss += __shfl_xor(ss, m, 64);
  __shared__ float red[4];
  if ((threadIdx.x & 63) == 0) red[threadIdx.x >> 6] = ss;
  __syncthreads();
  const float tot = red[0] + red[1] + red[2] + red[3];
  const float sc = rsqrtf(tot * (1.f / 1024.f) + 1e-6f);
#pragma unroll
  for (int j = 0; j < 4; ++j) {
    const int d = threadIdx.x + j * 256;
    out[(size_t)row * 1024 + d] = (__bf16)(v[j] * sc * wgt[d]);
  }
}

// ======== shared GEMM building blocks (128x128 tile, BK=32, 4 waves 2x2, bf16 B) ========
#define GEMM_PREAMBLE                                              \
  const int t = threadIdx.x;                                       \
  const int lane = t & 63;                                         \
  const int w = t >> 6, wr = w >> 1, wc = w & 1;                   \
  const int lr = lane & 15;                                        \
  const int lk = (lane >> 4) * 8;                                  \
  const int sr = t >> 2;                                           \
  const int scol = (t & 3) * 8;

#define FLAT_SWZ(BMC, BNC)                                         \
  const int chunk_ = (int)(gridDim.x >> 3);                        \
  const int wg_ = (blockIdx.x & 7) * chunk_ + (blockIdx.x >> 3);   \
  const int bm = wg_ % (BMC);                                      \
  const int rest_ = wg_ / (BMC);                                   \
  const int bn = rest_ % (BNC);                                    \
  const int ks = rest_ / (BNC);                                    \
  (void)ks;

#define GEMM_FRAGS_MFMA                                            \
  bf16x8 af[4], bfr[4];                                            \
  _Pragma("unroll") for (int m = 0; m < 4; ++m)                    \
    af[m] = *(const bf16x8*)&As[(wr * 64 + m * 16 + lr) * 32 + lk];\
  _Pragma("unroll") for (int n = 0; n < 4; ++n)                    \
    bfr[n] = *(const bf16x8*)&Bs[(wc * 64 + n * 16 + lr) * 32 + lk];\
  _Pragma("unroll") for (int m = 0; m < 4; ++m)                    \
    _Pragma("unroll") for (int n = 0; n < 4; ++n)                  \
      acc[m][n] = __builtin_amdgcn_mfma_f32_16x16x32_bf16(af[m], bfr[n], acc[m][n], 0, 0, 0);

// ---------------- generic GEMM (o-proj split-K), bf16 A and B ----------------
template <int EPI, int BMC, int BNC, int KSP>
__global__ __launch_bounds__(256) void gemm_bt(const __bf16* __restrict__ A,
                                               const __bf16* __restrict__ Bb,
                                               float* __restrict__ Cf,
                                               int K, int ldc) {
  __shared__ __bf16 As[128 * 32];
  __shared__ __bf16 Bs[128 * 32];
  GEMM_PREAMBLE
  FLAT_SWZ(BMC, BNC)
  const int klen = K / KSP;
  const int kbeg = ks * klen;

  const __bf16* a0 = A + (size_t)(bm * 128 + sr) * K + scol;
  const __bf16* a1 = A + (size_t)(bm * 128 + 64 + sr) * K + scol;
  const __bf16* bb0 = Bb + (size_t)(bn * 128 + sr) * K + scol;
  const __bf16* bb1 = Bb + (size_t)(bn * 128 + 64 + sr) * K + scol;

  f32x4 acc[4][4] = {};
  for (int k0 = kbeg; k0 < kbeg + klen; k0 += 32) {
    gld_lds16(a0 + k0, &As[t * 8]);
    gld_lds16(a1 + k0, &As[2048 + t * 8]);
    gld_lds16(bb0 + k0, &Bs[t * 8]);
    gld_lds16(bb1 + k0, &Bs[2048 + t * 8]);
    __syncthreads();
    GEMM_FRAGS_MFMA
    __syncthreads();
  }
  const int r0 = bm * 128 + wr * 64 + (lane >> 4) * 4;
  const int c0 = bn * 128 + wc * 64 + lr;
#pragma unroll
  for (int m = 0; m < 4; ++m)
#pragma unroll
    for (int r = 0; r < 4; ++r) {
      const size_t rowoff = (size_t)(r0 + m * 16 + r) * ldc;
#pragma unroll
      for (int n = 0; n < 4; ++n) {
        if (EPI == 3) Cf[rowoff + c0 + n * 16] = acc[m][n][r];
        else          atomicAdd(&Cf[rowoff + c0 + n * 16], acc[m][n][r]);
      }
    }
}

// ---------------- fused q+kv projection with bias + RoPE epilogue ----------------
__global__ __launch_bounds__(256) void qkv_gemm(const __bf16* __restrict__ A,
                                                const __bf16* __restrict__ qw,
                                                const __bf16* __restrict__ kvw,
                                                const float* __restrict__ q_b,
                                                const float* __restrict__ kv_b,
                                                __bf16* __restrict__ qb,
                                                __bf16* __restrict__ kvb) {
  const int K = 1024;
  __shared__ __bf16 As[128 * 32];
  __shared__ __bf16 Bs[128 * 32];
  GEMM_PREAMBLE
  FLAT_SWZ(16, 12)
  const bool isq = bn < 8;
  const int bnn = isq ? bn : bn - 8;
  const __bf16* Bw = (isq ? qw : kvw) + (size_t)(bnn * 128) * K;

  const __bf16* a0 = A + (size_t)(bm * 128 + sr) * K + scol;
  const __bf16* a1 = A + (size_t)(bm * 128 + 64 + sr) * K + scol;
  const __bf16* bb0 = Bw + (size_t)sr * K + scol;
  const __bf16* bb1 = Bw + (size_t)(64 + sr) * K + scol;

  f32x4 acc[4][4] = {};
  for (int k0 = 0; k0 < K; k0 += 32) {
    gld_lds16(a0 + k0, &As[t * 8]);
    gld_lds16(a1 + k0, &As[2048 + t * 8]);
    gld_lds16(bb0 + k0, &Bs[t * 8]);
    gld_lds16(bb1 + k0, &Bs[2048 + t * 8]);
    __syncthreads();
    GEMM_FRAGS_MFMA
    __syncthreads();
  }

  const int ldc = isq ? 1024 : 512;
  __bf16* out = isq ? qb : kvb;
  const float* bias = isq ? q_b : kv_b;
  const int cb = bnn * 128 + wc * 64;
  const bool dorope = isq || (cb < 256);
  float bv[4];
#pragma unroll
  for (int n = 0; n < 4; ++n) bv[n] = bias[cb + n * 16 + lr];
  float inv0 = __expf((float)lr * -0.28782313662425574f);
  float inv1 = __expf((float)(16 + lr) * -0.28782313662425574f);

  const int r0 = bm * 128 + wr * 64 + (lane >> 4) * 4;
#pragma unroll
  for (int m = 0; m < 4; ++m)
#pragma unroll
    for (int r = 0; r < 4; ++r) {
      const int row = r0 + m * 16 + r;
      float c4[4];
#pragma unroll
      for (int n = 0; n < 4; ++n) c4[n] = acc[m][n][r] + bv[n];
      if (dorope) {
        const float pos = (float)(row & 511);
        float sg, cg;
        __sincosf(pos * inv0, &sg, &cg);
        float x1 = c4[0], x2 = c4[2];
        c4[0] = x1 * cg - x2 * sg;
        c4[2] = x2 * cg + x1 * sg;
        __sincosf(pos * inv1, &sg, &cg);
        x1 = c4[1]; x2 = c4[3];
        c4[1] = x1 * cg - x2 * sg;
        c4[3] = x2 * cg + x1 * sg;
      }
      const size_t rowoff = (size_t)row * ldc;
#pragma unroll
      for (int n = 0; n < 4; ++n) out[rowoff + cb + n * 16 + lr] = (__bf16)c4[n];
    }
}

// ---------------- fused gate+up projection ----------------
__global__ __launch_bounds__(256) void gateup_gemm(const __bf16* __restrict__ A,
                                                   const __bf16* __restrict__ gw,
                                                   const __bf16* __restrict__ uw,
                                                   __bf16* __restrict__ gbuf,
                                                   __bf16* __restrict__ ubuf) {
  const int K = 1024;
  __shared__ __bf16 As[128 * 32];
  __shared__ __bf16 Bs[128 * 32];
  GEMM_PREAMBLE
  FLAT_SWZ(16, 44)
  const bool isg = bn < 22;
  const int bnn = isg ? bn : bn - 22;
  const __bf16* Bw = (isg ? gw : uw) + (size_t)(bnn * 128) * K;
  __bf16* out = isg ? gbuf : ubuf;

  const __bf16* a0 = A + (size_t)(bm * 128 + sr) * K + scol;
  const __bf16* a1 = A + (size_t)(bm * 128 + 64 + sr) * K + scol;
  const __bf16* bb0 = Bw + (size_t)sr * K + scol;
  const __bf16* bb1 = Bw + (size_t)(64 + sr) * K + scol;

  f32x4 acc[4][4] = {};
  for (int k0 = 0; k0 < K; k0 += 32) {
    gld_lds16(a0 + k0, &As[t * 8]);
    gld_lds16(a1 + k0, &As[2048 + t * 8]);
    gld_lds16(bb0 + k0, &Bs[t * 8]);
    gld_lds16(bb1 + k0, &Bs[2048 + t * 8]);
    __syncthreads();
    GEMM_FRAGS_MFMA
    __syncthreads();
  }
  const int r0 = bm * 128 + wr * 64 + (lane >> 4) * 4;
  const int c0 = bnn * 128 + wc * 64 + lr;
#pragma unroll
  for (int m = 0; m < 4; ++m)
#pragma unroll
    for (int r = 0; r < 4; ++r) {
      const size_t rowoff = (size_t)(r0 + m * 16 + r) * 2816;
#pragma unroll
      for (int n = 0; n < 4; ++n) out[rowoff + c0 + n * 16] = (__bf16)acc[m][n][r];
    }
}

// ---------------- down projection: fused SwiGLU A-staging, split-K x2 ----------------
__global__ __launch_bounds__(256) void down_gemm(const __bf16* __restrict__ g,
                                                 const __bf16* __restrict__ u,
                                                 const __bf16* __restrict__ Bb,
                                                 float* __restrict__ Cf) {
  const int K = 2816;
  __shared__ __bf16 As[128 * 32];
  __shared__ __bf16 Bs[128 * 32];
  GEMM_PREAMBLE
  FLAT_SWZ(16, 8)
  const int klen = 1408;
  const int kbeg = ks * klen;

  const size_t arow0 = (size_t)(bm * 128 + sr) * K + scol;
  const size_t arow1 = (size_t)(bm * 128 + 64 + sr) * K + scol;
  const __bf16* bb0 = Bb + (size_t)(bn * 128 + sr) * K + scol;
  const __bf16* bb1 = Bb + (size_t)(bn * 128 + 64 + sr) * K + scol;

  f32x4 acc[4][4] = {};
  for (int k0 = kbeg; k0 < kbeg + klen; k0 += 32) {
    {
      bf16x8 gv0 = *(const bf16x8*)(g + arow0 + k0);
      bf16x8 uv0 = *(const bf16x8*)(u + arow0 + k0);
      bf16x8 gv1 = *(const bf16x8*)(g + arow1 + k0);
      bf16x8 uv1 = *(const bf16x8*)(u + arow1 + k0);
      bf16x8 s0, s1;
#pragma unroll
      for (int j = 0; j < 8; ++j) {
        const float gf = (float)gv0[j];
        s0[j] = (__bf16)(gf / (1.f + __expf(-gf)) * (float)uv0[j]);
      }
#pragma unroll
      for (int j = 0; j < 8; ++j) {
        const float gf = (float)gv1[j];
        s1[j] = (__bf16)(gf / (1.f + __expf(-gf)) * (float)uv1[j]);
      }
      *(bf16x8*)&As[t * 8] = s0;
      *(bf16x8*)&As[2048 + t * 8] = s1;
    }
    gld_lds16(bb0 + k0, &Bs[t * 8]);
    gld_lds16(bb1 + k0, &Bs[2048 + t * 8]);
    __syncthreads();
    GEMM_FRAGS_MFMA
    __syncthreads();
  }
  const int r0 = bm * 128 + wr * 64 + (lane >> 4) * 4;
  const int c0 = bn * 128 + wc * 64 + lr;
#pragma unroll
  for (int m = 0; m < 4; ++m)
#pragma unroll
    for (int r = 0; r < 4; ++r) {
      const size_t rowoff = (size_t)(r0 + m * 16 + r) * 1024;
#pragma unroll
      for (int n = 0; n < 4; ++n) atomicAdd(&Cf[rowoff + c0 + n * 16], acc[m][n][r]);
    }
}

// ---------------- lm_head: 256x256 tile, BK=64, 8 waves, dbuf + counted vmcnt ----------------
// C[2048,32000] f32 = A[2048,1024] @ B[32000,1024]^T. Grid 1000 = 8 XCD x 125, bm-inner.
// LDS 128 KB: [dbuf][A0,A1,B0,B1][128x64] with byte ^= (row&7)<<4 swizzle (both sides).
__global__ __launch_bounds__(512, 2) void lmhead_gemm(const __bf16* __restrict__ A,
                                                      const __bf16* __restrict__ Bb,
                                                      float* __restrict__ C) {
  __shared__ __bf16 lds[2][4][8192];
  const int t = threadIdx.x;
  const int lane = t & 63;
  const int w = t >> 6;       // 0..7
  const int wr = w >> 2;      // 0..1 -> A half (128 rows)
  const int wc = w & 3;       // 0..3 -> 64-col strip
  const int lr = lane & 15;
  const int lg = lane >> 4;   // 0..3
  const int sx = (lr & 7) << 4;  // read-side swizzle XOR (bytes)

  const int wg = (blockIdx.x & 7) * 125 + (blockIdx.x >> 3);
  const int bm = wg & 7;      // 8 tiles of 256 rows
  const int bn = wg >> 3;     // 125 tiles of 256 cols

  // staging constants: thread covers lds bytes (t + j*512)*16 of each half-tile
  int srow[2], scol[2];
#pragma unroll
  for (int j = 0; j < 2; ++j) {
    const int q = (t + j * 512) * 16;
    const int row = q >> 7;                      // 128 B per row
    const int p = q ^ ((row & 7) << 4);          // inverse swizzle (involution)
    srow[j] = row;
    scol[j] = (p & 127) >> 1;                    // element col 0..56
  }

  auto STAGE = [&](int buf, int kt) {
#pragma unroll
    for (int ht = 0; ht < 4; ++ht) {
      const __bf16* base = (ht < 2)
          ? A + (size_t)(bm * 256 + ht * 128) * 1024
          : Bb + (size_t)(bn * 256 + (ht - 2) * 128) * 1024;
#pragma unroll
      for (int j = 0; j < 2; ++j) {
        gld_lds16(base + (size_t)srow[j] * 1024 + kt * 64 + scol[j],
                  (char*)&lds[buf][ht][0] + (size_t)(t + j * 512) * 16);
      }
    }
  };

  STAGE(0, 0);
  STAGE(1, 1);

  f32x4 acc[8][4] = {};
  for (int kt = 0; kt < 16; ++kt) {
    const int cur = kt & 1;
    if (kt < 15) asm volatile("s_waitcnt vmcnt(8)" ::: "memory");
    else         asm volatile("s_waitcnt vmcnt(0)" ::: "memory");
    __builtin_amdgcn_s_barrier();

    const char* Ab = (const char*)&lds[cur][wr][0];
    const char* Bbs = (const char*)&lds[cur][2 + (wc >> 1)][0];
    const int rB0 = (wc & 1) * 64;
#pragma unroll
    for (int ph = 0; ph < 4; ++ph) {
      const int m0 = (ph >> 1) * 4;
      const int n0 = (ph & 1) * 2;
      bf16x8 af[4][2], bfr[2][2];
#pragma unroll
      for (int mi = 0; mi < 4; ++mi)
#pragma unroll
        for (int ksl = 0; ksl < 2; ++ksl) {
          const int row = (m0 + mi) * 16 + lr;
          af[mi][ksl] = *(const bf16x8*)(Ab + ((row * 128 + ksl * 64 + lg * 16) ^ sx));
        }
#pragma unroll
      for (int ni = 0; ni < 2; ++ni)
#pragma unroll
        for (int ksl = 0; ksl < 2; ++ksl) {
          const int row = rB0 + (n0 + ni) * 16 + lr;
          bfr[ni][ksl] = *(const bf16x8*)(Bbs + ((row * 128 + ksl * 64 + lg * 16) ^ sx));
        }
      __builtin_amdgcn_s_setprio(1);
#pragma unroll
      for (int mi = 0; mi < 4; ++mi)
#pragma unroll
        for (int ni = 0; ni < 2; ++ni)
#pragma unroll
          for (int ksl = 0; ksl < 2; ++ksl)
            acc[m0 + mi][n0 + ni] = __builtin_amdgcn_mfma_f32_16x16x32_bf16(
                af[mi][ksl], bfr[ni][ksl], acc[m0 + mi][n0 + ni], 0, 0, 0);
      __builtin_amdgcn_s_setprio(0);
    }
    asm volatile("s_waitcnt lgkmcnt(0)" ::: "memory");
    __builtin_amdgcn_s_barrier();
    if (kt + 2 < 16) STAGE(cur, kt + 2);
  }

  const int r0 = bm * 256 + wr * 128 + lg * 4;
  const int c0 = bn * 256 + wc * 64 + lr;
#pragma unroll
  for (int m = 0; m < 8; ++m)
#pragma unroll
    for (int r = 0; r < 4; ++r) {
      float* crow = C + (size_t)(r0 + m * 16 + r) * 32000 + c0;
#pragma unroll
      for (int n = 0; n < 4; ++n)
        __builtin_nontemporal_store(acc[m][n][r], crow + n * 16);
    }
}

// ---------------- causal GQA flash attention (direct-K from L2, V via LDS transpose) ----------------
__global__ __launch_bounds__(256) void attn_kernel(const __bf16* __restrict__ q,
                                                   const __bf16* __restrict__ kv,
                                                   __bf16* __restrict__ o) {
  const int qt = blockIdx.x, hh = blockIdx.y, b = blockIdx.z;
  const int g = hh >> 2;
  const int t = threadIdx.x, lane = t & 63, w = t >> 6;
  const int lr = lane & 15, lg = lane >> 4;

  __shared__ __bf16 Vt[64 * 72];
  __shared__ __bf16 Ps[64 * 72];

  bf16x8 qa[2];
  {
    const size_t qoff = ((size_t)(b * 512 + qt * 64 + w * 16 + lr)) * 1024 + hh * 64;
    qa[0] = *(const bf16x8*)(q + qoff + lg * 8);
    qa[1] = *(const bf16x8*)(q + qoff + 32 + lg * 8);
  }

  f32x4 acc_o[4] = {};
  float mrow[4], lrow[4];
#pragma unroll
  for (int r = 0; r < 4; ++r) { mrow[r] = -1e30f; lrow[r] = 0.f; }

  const int srow = t >> 3;       // staging row 0..31
  const int sdv = (t & 7) * 8;   // staging col

  for (int kt = 0; kt <= qt; ++kt) {
    const size_t krow = ((size_t)(b * 512 + kt * 64 + srow)) * 512;
    // V -> Vt (transposed, padded stride 72)
    {
      const __bf16* vsrc = kv + krow + 256 + g * 64 + sdv;
      bf16x8 v0 = *(const bf16x8*)vsrc;
      bf16x8 v1 = *(const bf16x8*)(vsrc + 32 * 512);
#pragma unroll
      for (int j = 0; j < 8; ++j) Vt[(sdv + j) * 72 + srow] = v0[j];
#pragma unroll
      for (int j = 0; j < 8; ++j) Vt[(sdv + j) * 72 + srow + 32] = v1[j];
    }
    __syncthreads();

    // K fragments direct from global (L2-resident), hoisted
    bf16x8 kb[4][2];
#pragma unroll
    for (int nf = 0; nf < 4; ++nf)
#pragma unroll
      for (int kc = 0; kc < 2; ++kc)
        kb[nf][kc] = *(const bf16x8*)(kv +
            ((size_t)(b * 512 + kt * 64 + nf * 16 + lr)) * 512 + g * 64 + kc * 32 + lg * 8);

    f32x4 s[4] = {};
#pragma unroll
    for (int nf = 0; nf < 4; ++nf)
#pragma unroll
      for (int kc = 0; kc < 2; ++kc)
        s[nf] = __builtin_amdgcn_mfma_f32_16x16x32_bf16(qa[kc], kb[nf][kc], s[nf], 0, 0, 0);

    float pm[4][4], mx[4];
    const int qg = qt * 64 + w * 16 + lg * 4;
    const int kg = kt * 64 + lr;
#pragma unroll
    for (int r = 0; r < 4; ++r) mx[r] = -1e30f;
#pragma unroll
    for (int nf = 0; nf < 4; ++nf)
#pragma unroll
      for (int r = 0; r < 4; ++r) {
        float vv = s[nf][r] * 0.125f;
        vv = (kg + nf * 16 <= qg + r) ? vv : -1e30f;
        pm[nf][r] = vv;
        mx[r] = fmaxf(mx[r], vv);
      }
#pragma unroll
    for (int msk = 1; msk < 16; msk <<= 1)
#pragma unroll
      for (int r = 0; r < 4; ++r) mx[r] = fmaxf(mx[r], __shfl_xor(mx[r], msk, 64));

    float rs[4];
#pragma unroll
    for (int r = 0; r < 4; ++r) {
      const float mn = fmaxf(mrow[r], mx[r]);
      const float f = __expf(mrow[r] - mn);
      mrow[r] = mn;
      lrow[r] *= f;
#pragma unroll
      for (int df = 0; df < 4; ++df) acc_o[df][r] *= f;
      float rsum = 0.f;
#pragma unroll
      for (int nf = 0; nf < 4; ++nf) {
        const float pp = __expf(pm[nf][r] - mn);
        pm[nf][r] = pp;
        rsum += pp;
      }
      rs[r] = rsum;
    }
#pragma unroll
    for (int msk = 1; msk < 16; msk <<= 1)
#pragma unroll
      for (int r = 0; r < 4; ++r) rs[r] += __shfl_xor(rs[r], msk, 64);
#pragma unroll
    for (int r = 0; r < 4; ++r) lrow[r] += rs[r];

#pragma unroll
    for (int nf = 0; nf < 4; ++nf)
#pragma unroll
      for (int r = 0; r < 4; ++r)
        Ps[(w * 16 + lg * 4 + r) * 72 + nf * 16 + lr] = (__bf16)pm[nf][r];

#pragma unroll
    for (int df = 0; df < 4; ++df)
#pragma unroll
      for (int kc = 0; kc < 2; ++kc) {
        bf16x8 pa = *(const bf16x8*)&Ps[(w * 16 + lr) * 72 + kc * 32 + lg * 8];
        bf16x8 vb = *(const bf16x8*)&Vt[(df * 16 + lr) * 72 + kc * 32 + lg * 8];
        acc_o[df] = __builtin_amdgcn_mfma_f32_16x16x32_bf16(pa, vb, acc_o[df], 0, 0, 0);
      }
    __syncthreads();
  }

#pragma unroll
  for (int df = 0; df < 4; ++df)
#pragma unroll
    for (int r = 0; r < 4; ++r) {
      const int trow = qt * 64 + w * 16 + lg * 4 + r;
      o[((size_t)(b * 512 + trow)) * 1024 + hh * 64 + df * 16 + lr] =
          (__bf16)(acc_o[df][r] / lrow[r]);
    }
}

extern "C" void kernel_launch(void* const* d_in, const int* in_sizes, int n_in,
                              void* d_out, int out_size, void* d_ws, size_t ws_size,
                              hipStream_t stream) {
  const int* ids = (const int*)d_in[0];
  const float* emb_f = (const float*)d_in[1];
  const float* qw_f = (const float*)d_in[2];
  const float* q_b = (const float*)d_in[3];
  const float* kvw_f = (const float*)d_in[4];
  const float* kv_b = (const float*)d_in[5];
  const float* ow_f = (const float*)d_in[6];
  const float* ln1 = (const float*)d_in[7];
  const float* ln2 = (const float*)d_in[8];
  const float* gw_f = (const float*)d_in[9];
  const float* uw_f = (const float*)d_in[10];
  const float* dw_f = (const float*)d_in[11];
  const float* lw = (const float*)d_in[12];
  float* out = (float*)d_out;  // f32 logits

  char* p = (char*)d_ws;
  float* x = (float*)p;        p += (size_t)2048 * 1024 * 4;
  __bf16* h = (__bf16*)p;      p += (size_t)2048 * 1024 * 2;
  __bf16* qb = (__bf16*)p;     p += (size_t)2048 * 1024 * 2;
  __bf16* kvb = (__bf16*)p;    p += (size_t)2048 * 512 * 2;
  __bf16* ao = (__bf16*)p;     p += (size_t)2048 * 1024 * 2;
  __bf16* gb = (__bf16*)p;     p += (size_t)2048 * 2816 * 2;
  __bf16* ub = (__bf16*)p;     p += (size_t)2048 * 2816 * 2;
  __bf16* emb_b = (__bf16*)p;  p += (size_t)32000 * 1024 * 2;
  __bf16* qw_b = (__bf16*)p;   p += (size_t)4 * 1024 * 1024 * 2;
  __bf16* kvw_b = (__bf16*)p;  p += (size_t)4 * 512 * 1024 * 2;
  __bf16* ow_b = (__bf16*)p;   p += (size_t)4 * 1024 * 1024 * 2;
  __bf16* gw_b = (__bf16*)p;   p += (size_t)4 * 2816 * 1024 * 2;
  __bf16* uw_b = (__bf16*)p;   p += (size_t)4 * 2816 * 1024 * 2;
  __bf16* dw_b = (__bf16*)p;   p += (size_t)4 * 2816 * 1024 * 2;

  cvt_kernel<<<2048, 256, 0, stream>>>(emb_f, emb_b, 32000 * 1024 / 4);
  cvt_kernel<<<1024, 256, 0, stream>>>(qw_f, qw_b, 4 * 1024 * 1024 / 4);
  cvt_kernel<<<1024, 256, 0, stream>>>(kvw_f, kvw_b, 4 * 512 * 1024 / 4);
  cvt_kernel<<<1024, 256, 0, stream>>>(ow_f, ow_b, 4 * 1024 * 1024 / 4);
  cvt_kernel<<<1024, 256, 0, stream>>>(gw_f, gw_b, 4 * 2816 * 1024 / 4);
  cvt_kernel<<<1024, 256, 0, stream>>>(uw_f, uw_b, 4 * 2816 * 1024 / 4);
  cvt_kernel<<<1024, 256, 0, stream>>>(dw_f, dw_b, 4 * 2816 * 1024 / 4);

  embed_kernel<<<2048, 256, 0, stream>>>(ids, emb_f, x);
  for (int l = 0; l < 4; ++l) {
    rmsnorm_kernel<<<2048, 256, 0, stream>>>(x, ln1 + l * 1024, h);
    qkv_gemm<<<192, 256, 0, stream>>>(
        h, qw_b + (size_t)l * 1024 * 1024, kvw_b + (size_t)l * 512 * 1024,
        q_b + l * 1024, kv_b + l * 512, qb, kvb);
    attn_kernel<<<dim3(8, 16, 4), 256, 0, stream>>>(qb, kvb, ao);
    gemm_bt<4, 16, 8, 2><<<256, 256, 0, stream>>>(
        ao, ow_b + (size_t)l * 1024 * 1024, x, 1024, 1024);
    rmsnorm_kernel<<<2048, 256, 0, stream>>>(x, ln2 + l * 1024, h);
    gateup_gemm<<<704, 256, 0, stream>>>(
        h, gw_b + (size_t)l * 2816 * 1024, uw_b + (size_t)l * 2816 * 1024, gb, ub);
    down_gemm<<<256, 256, 0, stream>>>(
        gb, ub, dw_b + (size_t)l * 1024 * 2816, x);
  }
  rmsnorm_kernel<<<2048, 256, 0, stream>>>(x, lw, h);
  lmhead_gemm<<<1000, 512, 0, stream>>>(h, emb_b, out);
}

// Round 8
// 1053.714 us; speedup vs baseline: 1.6903x; 1.0100x over previous
//
#include <hip/hip_runtime.h>
#include <hip/hip_bf16.h>
#include <stdint.h>

// Model dims: L=4, D=1024, H=16, G=4, HS=64, I=2816, V=32000, B=4, T=512. NT = 2048.
// Inputs: f32 (+ int32 ids). Output: f32 logits [B,T,V].

typedef __bf16 bf16x8 __attribute__((ext_vector_type(8)));
typedef __bf16 bf16x4 __attribute__((ext_vector_type(4)));
typedef float  f32x4  __attribute__((ext_vector_type(4)));

#define AS1 __attribute__((address_space(1)))
#define AS3 __attribute__((address_space(3)))

__device__ __forceinline__ void gld_lds16(const void* g, void* l) {
  __builtin_amdgcn_global_load_lds((const AS1 void*)g, (AS3 void*)l, 16, 0, 0);
}

// ---------------- f32 -> bf16 convert (vectorized, grid-stride, nt loads) ----------------
__global__ __launch_bounds__(256) void cvt_kernel(const float* __restrict__ in,
                                                  __bf16* __restrict__ out, int n4) {
  for (int i = blockIdx.x * 256 + threadIdx.x; i < n4; i += gridDim.x * 256) {
    f32x4 v = __builtin_nontemporal_load(&((const f32x4*)in)[i]);
    bf16x4 o;
#pragma unroll
    for (int j = 0; j < 4; ++j) o[j] = (__bf16)v[j];
    ((bf16x4*)out)[i] = o;
  }
}

// ---------------- embedding lookup ----------------
__global__ __launch_bounds__(256) void embed_kernel(const int* __restrict__ ids,
                                                    const float* __restrict__ emb,
                                                    float* __restrict__ x) {
  const int tok = blockIdx.x;
  const float* src = emb + (size_t)ids[tok] * 1024;
  float* dst = x + (size_t)tok * 1024;
#pragma unroll
  for (int j = 0; j < 4; ++j) {
    const int d = threadIdx.x + j * 256;
    dst[d] = src[d];
  }
}

// ---------------- RMSNorm ----------------
__global__ __launch_bounds__(256) void rmsnorm_kernel(const float* __restrict__ x,
                                                      const float* __restrict__ wgt,
                                                      __bf16* __restrict__ out) {
  const int row = blockIdx.x;
  const float* xr = x + (size_t)row * 1024;
  float v[4];
  float ss = 0.f;
#pragma unroll
  for (int j = 0; j < 4; ++j) { v[j] = xr[threadIdx.x + j * 256]; ss += v[j] * v[j]; }
#pragma unroll
  for (int m = 1; m < 64; m <<= 1) ss += __shfl_xor(ss, m, 64);
  __shared__ float red[4];
  if ((threadIdx.x & 63) == 0) red[threadIdx.x >> 6] = ss;
  __syncthreads();
  const float tot = red[0] + red[1] + red[2] + red[3];
  const float sc = rsqrtf(tot * (1.f / 1024.f) + 1e-6f);
#pragma unroll
  for (int j = 0; j < 4; ++j) {
    const int d = threadIdx.x + j * 256;
    out[(size_t)row * 1024 + d] = (__bf16)(v[j] * sc * wgt[d]);
  }
}

// ======== shared GEMM building blocks (128x128 tile, BK=32, 4 waves 2x2, bf16 B) ========
#define GEMM_PREAMBLE                                              \
  const int t = threadIdx.x;                                       \
  const int lane = t & 63;                                         \
  const int w = t >> 6, wr = w >> 1, wc = w & 1;                   \
  const int lr = lane & 15;                                        \
  const int lk = (lane >> 4) * 8;                                  \
  const int sr = t >> 2;                                           \
  const int scol = (t & 3) * 8;

#define FLAT_SWZ(BMC, BNC)                                         \
  const int chunk_ = (int)(gridDim.x >> 3);                        \
  const int wg_ = (blockIdx.x & 7) * chunk_ + (blockIdx.x >> 3);   \
  const int bm = wg_ % (BMC);                                      \
  const int rest_ = wg_ / (BMC);                                   \
  const int bn = rest_ % (BNC);                                    \
  const int ks = rest_ / (BNC);                                    \
  (void)ks;

#define GEMM_FRAGS_MFMA                                            \
  bf16x8 af[4], bfr[4];                                            \
  _Pragma("unroll") for (int m = 0; m < 4; ++m)                    \
    af[m] = *(const bf16x8*)&As[(wr * 64 + m * 16 + lr) * 32 + lk];\
  _Pragma("unroll") for (int n = 0; n < 4; ++n)                    \
    bfr[n] = *(const bf16x8*)&Bs[(wc * 64 + n * 16 + lr) * 32 + lk];\
  _Pragma("unroll") for (int m = 0; m < 4; ++m)                    \
    _Pragma("unroll") for (int n = 0; n < 4; ++n)                  \
      acc[m][n] = __builtin_amdgcn_mfma_f32_16x16x32_bf16(af[m], bfr[n], acc[m][n], 0, 0, 0);

// ---------------- generic GEMM (o-proj split-K), bf16 A and B ----------------
template <int EPI, int BMC, int BNC, int KSP>
__global__ __launch_bounds__(256) void gemm_bt(const __bf16* __restrict__ A,
                                               const __bf16* __restrict__ Bb,
                                               float* __restrict__ Cf,
                                               int K, int ldc) {
  __shared__ __bf16 As[128 * 32];
  __shared__ __bf16 Bs[128 * 32];
  GEMM_PREAMBLE
  FLAT_SWZ(BMC, BNC)
  const int klen = K / KSP;
  const int kbeg = ks * klen;

  const __bf16* a0 = A + (size_t)(bm * 128 + sr) * K + scol;
  const __bf16* a1 = A + (size_t)(bm * 128 + 64 + sr) * K + scol;
  const __bf16* bb0 = Bb + (size_t)(bn * 128 + sr) * K + scol;
  const __bf16* bb1 = Bb + (size_t)(bn * 128 + 64 + sr) * K + scol;

  f32x4 acc[4][4] = {};
  for (int k0 = kbeg; k0 < kbeg + klen; k0 += 32) {
    gld_lds16(a0 + k0, &As[t * 8]);
    gld_lds16(a1 + k0, &As[2048 + t * 8]);
    gld_lds16(bb0 + k0, &Bs[t * 8]);
    gld_lds16(bb1 + k0, &Bs[2048 + t * 8]);
    __syncthreads();
    GEMM_FRAGS_MFMA
    __syncthreads();
  }
  const int r0 = bm * 128 + wr * 64 + (lane >> 4) * 4;
  const int c0 = bn * 128 + wc * 64 + lr;
#pragma unroll
  for (int m = 0; m < 4; ++m)
#pragma unroll
    for (int r = 0; r < 4; ++r) {
      const size_t rowoff = (size_t)(r0 + m * 16 + r) * ldc;
#pragma unroll
      for (int n = 0; n < 4; ++n) {
        if (EPI == 3) Cf[rowoff + c0 + n * 16] = acc[m][n][r];
        else          atomicAdd(&Cf[rowoff + c0 + n * 16], acc[m][n][r]);
      }
    }
}

// ---------------- fused q+kv projection with bias + RoPE epilogue ----------------
__global__ __launch_bounds__(256) void qkv_gemm(const __bf16* __restrict__ A,
                                                const __bf16* __restrict__ qw,
                                                const __bf16* __restrict__ kvw,
                                                const float* __restrict__ q_b,
                                                const float* __restrict__ kv_b,
                                                __bf16* __restrict__ qb,
                                                __bf16* __restrict__ kvb) {
  const int K = 1024;
  __shared__ __bf16 As[128 * 32];
  __shared__ __bf16 Bs[128 * 32];
  GEMM_PREAMBLE
  FLAT_SWZ(16, 12)
  const bool isq = bn < 8;
  const int bnn = isq ? bn : bn - 8;
  const __bf16* Bw = (isq ? qw : kvw) + (size_t)(bnn * 128) * K;

  const __bf16* a0 = A + (size_t)(bm * 128 + sr) * K + scol;
  const __bf16* a1 = A + (size_t)(bm * 128 + 64 + sr) * K + scol;
  const __bf16* bb0 = Bw + (size_t)sr * K + scol;
  const __bf16* bb1 = Bw + (size_t)(64 + sr) * K + scol;

  f32x4 acc[4][4] = {};
  for (int k0 = 0; k0 < K; k0 += 32) {
    gld_lds16(a0 + k0, &As[t * 8]);
    gld_lds16(a1 + k0, &As[2048 + t * 8]);
    gld_lds16(bb0 + k0, &Bs[t * 8]);
    gld_lds16(bb1 + k0, &Bs[2048 + t * 8]);
    __syncthreads();
    GEMM_FRAGS_MFMA
    __syncthreads();
  }

  const int ldc = isq ? 1024 : 512;
  __bf16* out = isq ? qb : kvb;
  const float* bias = isq ? q_b : kv_b;
  const int cb = bnn * 128 + wc * 64;
  const bool dorope = isq || (cb < 256);
  float bv[4];
#pragma unroll
  for (int n = 0; n < 4; ++n) bv[n] = bias[cb + n * 16 + lr];
  float inv0 = __expf((float)lr * -0.28782313662425574f);
  float inv1 = __expf((float)(16 + lr) * -0.28782313662425574f);

  const int r0 = bm * 128 + wr * 64 + (lane >> 4) * 4;
#pragma unroll
  for (int m = 0; m < 4; ++m)
#pragma unroll
    for (int r = 0; r < 4; ++r) {
      const int row = r0 + m * 16 + r;
      float c4[4];
#pragma unroll
      for (int n = 0; n < 4; ++n) c4[n] = acc[m][n][r] + bv[n];
      if (dorope) {
        const float pos = (float)(row & 511);
        float sg, cg;
        __sincosf(pos * inv0, &sg, &cg);
        float x1 = c4[0], x2 = c4[2];
        c4[0] = x1 * cg - x2 * sg;
        c4[2] = x2 * cg + x1 * sg;
        __sincosf(pos * inv1, &sg, &cg);
        x1 = c4[1]; x2 = c4[3];
        c4[1] = x1 * cg - x2 * sg;
        c4[3] = x2 * cg + x1 * sg;
      }
      const size_t rowoff = (size_t)row * ldc;
#pragma unroll
      for (int n = 0; n < 4; ++n) out[rowoff + cb + n * 16 + lr] = (__bf16)c4[n];
    }
}

// ---------------- fused gate+up projection ----------------
__global__ __launch_bounds__(256) void gateup_gemm(const __bf16* __restrict__ A,
                                                   const __bf16* __restrict__ gw,
                                                   const __bf16* __restrict__ uw,
                                                   __bf16* __restrict__ gbuf,
                                                   __bf16* __restrict__ ubuf) {
  const int K = 1024;
  __shared__ __bf16 As[128 * 32];
  __shared__ __bf16 Bs[128 * 32];
  GEMM_PREAMBLE
  FLAT_SWZ(16, 44)
  const bool isg = bn < 22;
  const int bnn = isg ? bn : bn - 22;
  const __bf16* Bw = (isg ? gw : uw) + (size_t)(bnn * 128) * K;
  __bf16* out = isg ? gbuf : ubuf;

  const __bf16* a0 = A + (size_t)(bm * 128 + sr) * K + scol;
  const __bf16* a1 = A + (size_t)(bm * 128 + 64 + sr) * K + scol;
  const __bf16* bb0 = Bw + (size_t)sr * K + scol;
  const __bf16* bb1 = Bw + (size_t)(64 + sr) * K + scol;

  f32x4 acc[4][4] = {};
  for (int k0 = 0; k0 < K; k0 += 32) {
    gld_lds16(a0 + k0, &As[t * 8]);
    gld_lds16(a1 + k0, &As[2048 + t * 8]);
    gld_lds16(bb0 + k0, &Bs[t * 8]);
    gld_lds16(bb1 + k0, &Bs[2048 + t * 8]);
    __syncthreads();
    GEMM_FRAGS_MFMA
    __syncthreads();
  }
  const int r0 = bm * 128 + wr * 64 + (lane >> 4) * 4;
  const int c0 = bnn * 128 + wc * 64 + lr;
#pragma unroll
  for (int m = 0; m < 4; ++m)
#pragma unroll
    for (int r = 0; r < 4; ++r) {
      const size_t rowoff = (size_t)(r0 + m * 16 + r) * 2816;
#pragma unroll
      for (int n = 0; n < 4; ++n) out[rowoff + c0 + n * 16] = (__bf16)acc[m][n][r];
    }
}

// ---------------- down projection: fused SwiGLU A-staging, split-K x2 ----------------
__global__ __launch_bounds__(256) void down_gemm(const __bf16* __restrict__ g,
                                                 const __bf16* __restrict__ u,
                                                 const __bf16* __restrict__ Bb,
                                                 float* __restrict__ Cf) {
  const int K = 2816;
  __shared__ __bf16 As[128 * 32];
  __shared__ __bf16 Bs[128 * 32];
  GEMM_PREAMBLE
  FLAT_SWZ(16, 8)
  const int klen = 1408;
  const int kbeg = ks * klen;

  const size_t arow0 = (size_t)(bm * 128 + sr) * K + scol;
  const size_t arow1 = (size_t)(bm * 128 + 64 + sr) * K + scol;
  const __bf16* bb0 = Bb + (size_t)(bn * 128 + sr) * K + scol;
  const __bf16* bb1 = Bb + (size_t)(bn * 128 + 64 + sr) * K + scol;

  f32x4 acc[4][4] = {};
  for (int k0 = kbeg; k0 < kbeg + klen; k0 += 32) {
    {
      bf16x8 gv0 = *(const bf16x8*)(g + arow0 + k0);
      bf16x8 uv0 = *(const bf16x8*)(u + arow0 + k0);
      bf16x8 gv1 = *(const bf16x8*)(g + arow1 + k0);
      bf16x8 uv1 = *(const bf16x8*)(u + arow1 + k0);
      bf16x8 s0, s1;
#pragma unroll
      for (int j = 0; j < 8; ++j) {
        const float gf = (float)gv0[j];
        s0[j] = (__bf16)(gf / (1.f + __expf(-gf)) * (float)uv0[j]);
      }
#pragma unroll
      for (int j = 0; j < 8; ++j) {
        const float gf = (float)gv1[j];
        s1[j] = (__bf16)(gf / (1.f + __expf(-gf)) * (float)uv1[j]);
      }
      *(bf16x8*)&As[t * 8] = s0;
      *(bf16x8*)&As[2048 + t * 8] = s1;
    }
    gld_lds16(bb0 + k0, &Bs[t * 8]);
    gld_lds16(bb1 + k0, &Bs[2048 + t * 8]);
    __syncthreads();
    GEMM_FRAGS_MFMA
    __syncthreads();
  }
  const int r0 = bm * 128 + wr * 64 + (lane >> 4) * 4;
  const int c0 = bn * 128 + wc * 64 + lr;
#pragma unroll
  for (int m = 0; m < 4; ++m)
#pragma unroll
    for (int r = 0; r < 4; ++r) {
      const size_t rowoff = (size_t)(r0 + m * 16 + r) * 1024;
#pragma unroll
      for (int n = 0; n < 4; ++n) atomicAdd(&Cf[rowoff + c0 + n * 16], acc[m][n][r]);
    }
}

// ---------------- lm_head: 256x256 tile, BK=64, 8 waves, dbuf + counted vmcnt ----------------
// C[2048,32000] f32 = A[2048,1024] @ B[32000,1024]^T. Grid 1000 = 8 XCD x 125, bm-inner.
// LDS 128 KB: [dbuf][A0,A1,B0,B1][128x64] with byte ^= (row&7)<<4 swizzle (both sides).
// Fragment reads DEDUP'd: 16 A-frags loaded once per K-tile; B-frags once per n-pair phase
// (24 unique ds_read_b128/wave/K-tile vs 48 in the previous 4-phase version).
__global__ __launch_bounds__(512, 2) void lmhead_gemm(const __bf16* __restrict__ A,
                                                      const __bf16* __restrict__ Bb,
                                                      float* __restrict__ C) {
  __shared__ __bf16 lds[2][4][8192];
  const int t = threadIdx.x;
  const int lane = t & 63;
  const int w = t >> 6;       // 0..7
  const int wr = w >> 2;      // 0..1 -> A half (128 rows)
  const int wc = w & 3;       // 0..3 -> 64-col strip
  const int lr = lane & 15;
  const int lg = lane >> 4;   // 0..3
  const int sx = (lr & 7) << 4;  // read-side swizzle XOR (bytes)

  const int wg = (blockIdx.x & 7) * 125 + (blockIdx.x >> 3);
  const int bm = wg & 7;      // 8 tiles of 256 rows
  const int bn = wg >> 3;     // 125 tiles of 256 cols

  // staging constants: thread covers lds bytes (t + j*512)*16 of each half-tile
  int srow[2], scol[2];
#pragma unroll
  for (int j = 0; j < 2; ++j) {
    const int q = (t + j * 512) * 16;
    const int row = q >> 7;                      // 128 B per row
    const int p = q ^ ((row & 7) << 4);          // inverse swizzle (involution)
    srow[j] = row;
    scol[j] = (p & 127) >> 1;                    // element col 0..56
  }

  auto STAGE = [&](int buf, int kt) {
#pragma unroll
    for (int ht = 0; ht < 4; ++ht) {
      const __bf16* base = (ht < 2)
          ? A + (size_t)(bm * 256 + ht * 128) * 1024
          : Bb + (size_t)(bn * 256 + (ht - 2) * 128) * 1024;
#pragma unroll
      for (int j = 0; j < 2; ++j) {
        gld_lds16(base + (size_t)srow[j] * 1024 + kt * 64 + scol[j],
                  (char*)&lds[buf][ht][0] + (size_t)(t + j * 512) * 16);
      }
    }
  };

  STAGE(0, 0);
  STAGE(1, 1);

  f32x4 acc[8][4] = {};
  for (int kt = 0; kt < 16; ++kt) {
    const int cur = kt & 1;
    if (kt < 15) asm volatile("s_waitcnt vmcnt(8)" ::: "memory");
    else         asm volatile("s_waitcnt vmcnt(0)" ::: "memory");
    __builtin_amdgcn_s_barrier();

    const char* Ab = (const char*)&lds[cur][wr][0];
    const char* Bbs = (const char*)&lds[cur][2 + (wc >> 1)][0];
    const int rB0 = (wc & 1) * 64;

    // all 16 A-fragments, loaded once
    bf16x8 af[8][2];
#pragma unroll
    for (int mi = 0; mi < 8; ++mi)
#pragma unroll
      for (int ksl = 0; ksl < 2; ++ksl) {
        const int row = mi * 16 + lr;
        af[mi][ksl] = *(const bf16x8*)(Ab + ((row * 128 + ksl * 64 + lg * 16) ^ sx));
      }
    // two n-pair phases, each loads its 4 B-fragments once, then 32 MFMA
#pragma unroll
    for (int np = 0; np < 2; ++np) {
      bf16x8 bfr[2][2];
#pragma unroll
      for (int ni = 0; ni < 2; ++ni)
#pragma unroll
        for (int ksl = 0; ksl < 2; ++ksl) {
          const int row = rB0 + (np * 2 + ni) * 16 + lr;
          bfr[ni][ksl] = *(const bf16x8*)(Bbs + ((row * 128 + ksl * 64 + lg * 16) ^ sx));
        }
      __builtin_amdgcn_s_setprio(1);
#pragma unroll
      for (int mi = 0; mi < 8; ++mi)
#pragma unroll
        for (int ni = 0; ni < 2; ++ni)
#pragma unroll
          for (int ksl = 0; ksl < 2; ++ksl)
            acc[mi][np * 2 + ni] = __builtin_amdgcn_mfma_f32_16x16x32_bf16(
                af[mi][ksl], bfr[ni][ksl], acc[mi][np * 2 + ni], 0, 0, 0);
      __builtin_amdgcn_s_setprio(0);
    }
    asm volatile("s_waitcnt lgkmcnt(0)" ::: "memory");
    __builtin_amdgcn_s_barrier();
    if (kt + 2 < 16) STAGE(cur, kt + 2);
  }

  const int r0 = bm * 256 + wr * 128 + lg * 4;
  const int c0 = bn * 256 + wc * 64 + lr;
#pragma unroll
  for (int m = 0; m < 8; ++m)
#pragma unroll
    for (int r = 0; r < 4; ++r) {
      float* crow = C + (size_t)(r0 + m * 16 + r) * 32000 + c0;
#pragma unroll
      for (int n = 0; n < 4; ++n)
        __builtin_nontemporal_store(acc[m][n][r], crow + n * 16);
    }
}

// ---------------- causal GQA flash attention (direct-K from L2, V via LDS transpose) ----------------
__global__ __launch_bounds__(256) void attn_kernel(const __bf16* __restrict__ q,
                                                   const __bf16* __restrict__ kv,
                                                   __bf16* __restrict__ o) {
  const int qt = blockIdx.x, hh = blockIdx.y, b = blockIdx.z;
  const int g = hh >> 2;
  const int t = threadIdx.x, lane = t & 63, w = t >> 6;
  const int lr = lane & 15, lg = lane >> 4;

  __shared__ __bf16 Vt[64 * 72];
  __shared__ __bf16 Ps[64 * 72];

  bf16x8 qa[2];
  {
    const size_t qoff = ((size_t)(b * 512 + qt * 64 + w * 16 + lr)) * 1024 + hh * 64;
    qa[0] = *(const bf16x8*)(q + qoff + lg * 8);
    qa[1] = *(const bf16x8*)(q + qoff + 32 + lg * 8);
  }

  f32x4 acc_o[4] = {};
  float mrow[4], lrow[4];
#pragma unroll
  for (int r = 0; r < 4; ++r) { mrow[r] = -1e30f; lrow[r] = 0.f; }

  const int srow = t >> 3;       // staging row 0..31
  const int sdv = (t & 7) * 8;   // staging col

  for (int kt = 0; kt <= qt; ++kt) {
    const size_t krow = ((size_t)(b * 512 + kt * 64 + srow)) * 512;
    // V -> Vt (transposed, padded stride 72)
    {
      const __bf16* vsrc = kv + krow + 256 + g * 64 + sdv;
      bf16x8 v0 = *(const bf16x8*)vsrc;
      bf16x8 v1 = *(const bf16x8*)(vsrc + 32 * 512);
#pragma unroll
      for (int j = 0; j < 8; ++j) Vt[(sdv + j) * 72 + srow] = v0[j];
#pragma unroll
      for (int j = 0; j < 8; ++j) Vt[(sdv + j) * 72 + srow + 32] = v1[j];
    }
    __syncthreads();

    // K fragments direct from global (L2-resident), hoisted
    bf16x8 kb[4][2];
#pragma unroll
    for (int nf = 0; nf < 4; ++nf)
#pragma unroll
      for (int kc = 0; kc < 2; ++kc)
        kb[nf][kc] = *(const bf16x8*)(kv +
            ((size_t)(b * 512 + kt * 64 + nf * 16 + lr)) * 512 + g * 64 + kc * 32 + lg * 8);

    f32x4 s[4] = {};
#pragma unroll
    for (int nf = 0; nf < 4; ++nf)
#pragma unroll
      for (int kc = 0; kc < 2; ++kc)
        s[nf] = __builtin_amdgcn_mfma_f32_16x16x32_bf16(qa[kc], kb[nf][kc], s[nf], 0, 0, 0);

    float pm[4][4], mx[4];
    const int qg = qt * 64 + w * 16 + lg * 4;
    const int kg = kt * 64 + lr;
#pragma unroll
    for (int r = 0; r < 4; ++r) mx[r] = -1e30f;
#pragma unroll
    for (int nf = 0; nf < 4; ++nf)
#pragma unroll
      for (int r = 0; r < 4; ++r) {
        float vv = s[nf][r] * 0.125f;
        vv = (kg + nf * 16 <= qg + r) ? vv : -1e30f;
        pm[nf][r] = vv;
        mx[r] = fmaxf(mx[r], vv);
      }
#pragma unroll
    for (int msk = 1; msk < 16; msk <<= 1)
#pragma unroll
      for (int r = 0; r < 4; ++r) mx[r] = fmaxf(mx[r], __shfl_xor(mx[r], msk, 64));

    float rs[4];
#pragma unroll
    for (int r = 0; r < 4; ++r) {
      const float mn = fmaxf(mrow[r], mx[r]);
      const float f = __expf(mrow[r] - mn);
      mrow[r] = mn;
      lrow[r] *= f;
#pragma unroll
      for (int df = 0; df < 4; ++df) acc_o[df][r] *= f;
      float rsum = 0.f;
#pragma unroll
      for (int nf = 0; nf < 4; ++nf) {
        const float pp = __expf(pm[nf][r] - mn);
        pm[nf][r] = pp;
        rsum += pp;
      }
      rs[r] = rsum;
    }
#pragma unroll
    for (int msk = 1; msk < 16; msk <<= 1)
#pragma unroll
      for (int r = 0; r < 4; ++r) rs[r] += __shfl_xor(rs[r], msk, 64);
#pragma unroll
    for (int r = 0; r < 4; ++r) lrow[r] += rs[r];

#pragma unroll
    for (int nf = 0; nf < 4; ++nf)
#pragma unroll
      for (int r = 0; r < 4; ++r)
        Ps[(w * 16 + lg * 4 + r) * 72 + nf * 16 + lr] = (__bf16)pm[nf][r];

#pragma unroll
    for (int df = 0; df < 4; ++df)
#pragma unroll
      for (int kc = 0; kc < 2; ++kc) {
        bf16x8 pa = *(const bf16x8*)&Ps[(w * 16 + lr) * 72 + kc * 32 + lg * 8];
        bf16x8 vb = *(const bf16x8*)&Vt[(df * 16 + lr) * 72 + kc * 32 + lg * 8];
        acc_o[df] = __builtin_amdgcn_mfma_f32_16x16x32_bf16(pa, vb, acc_o[df], 0, 0, 0);
      }
    __syncthreads();
  }

#pragma unroll
  for (int df = 0; df < 4; ++df)
#pragma unroll
    for (int r = 0; r < 4; ++r) {
      const int trow = qt * 64 + w * 16 + lg * 4 + r;
      o[((size_t)(b * 512 + trow)) * 1024 + hh * 64 + df * 16 + lr] =
          (__bf16)(acc_o[df][r] / lrow[r]);
    }
}

extern "C" void kernel_launch(void* const* d_in, const int* in_sizes, int n_in,
                              void* d_out, int out_size, void* d_ws, size_t ws_size,
                              hipStream_t stream) {
  const int* ids = (const int*)d_in[0];
  const float* emb_f = (const float*)d_in[1];
  const float* qw_f = (const float*)d_in[2];
  const float* q_b = (const float*)d_in[3];
  const float* kvw_f = (const float*)d_in[4];
  const float* kv_b = (const float*)d_in[5];
  const float* ow_f = (const float*)d_in[6];
  const float* ln1 = (const float*)d_in[7];
  const float* ln2 = (const float*)d_in[8];
  const float* gw_f = (const float*)d_in[9];
  const float* uw_f = (const float*)d_in[10];
  const float* dw_f = (const float*)d_in[11];
  const float* lw = (const float*)d_in[12];
  float* out = (float*)d_out;  // f32 logits

  char* p = (char*)d_ws;
  float* x = (float*)p;        p += (size_t)2048 * 1024 * 4;
  __bf16* h = (__bf16*)p;      p += (size_t)2048 * 1024 * 2;
  __bf16* qb = (__bf16*)p;     p += (size_t)2048 * 1024 * 2;
  __bf16* kvb = (__bf16*)p;    p += (size_t)2048 * 512 * 2;
  __bf16* ao = (__bf16*)p;     p += (size_t)2048 * 1024 * 2;
  __bf16* gb = (__bf16*)p;     p += (size_t)2048 * 2816 * 2;
  __bf16* ub = (__bf16*)p;     p += (size_t)2048 * 2816 * 2;
  __bf16* emb_b = (__bf16*)p;  p += (size_t)32000 * 1024 * 2;
  __bf16* qw_b = (__bf16*)p;   p += (size_t)4 * 1024 * 1024 * 2;
  __bf16* kvw_b = (__bf16*)p;  p += (size_t)4 * 512 * 1024 * 2;
  __bf16* ow_b = (__bf16*)p;   p += (size_t)4 * 1024 * 1024 * 2;
  __bf16* gw_b = (__bf16*)p;   p += (size_t)4 * 2816 * 1024 * 2;
  __bf16* uw_b = (__bf16*)p;   p += (size_t)4 * 2816 * 1024 * 2;
  __bf16* dw_b = (__bf16*)p;   p += (size_t)4 * 2816 * 1024 * 2;

  cvt_kernel<<<2048, 256, 0, stream>>>(emb_f, emb_b, 32000 * 1024 / 4);
  cvt_kernel<<<1024, 256, 0, stream>>>(qw_f, qw_b, 4 * 1024 * 1024 / 4);
  cvt_kernel<<<1024, 256, 0, stream>>>(kvw_f, kvw_b, 4 * 512 * 1024 / 4);
  cvt_kernel<<<1024, 256, 0, stream>>>(ow_f, ow_b, 4 * 1024 * 1024 / 4);
  cvt_kernel<<<1024, 256, 0, stream>>>(gw_f, gw_b, 4 * 2816 * 1024 / 4);
  cvt_kernel<<<1024, 256, 0, stream>>>(uw_f, uw_b, 4 * 2816 * 1024 / 4);
  cvt_kernel<<<1024, 256, 0, stream>>>(dw_f, dw_b, 4 * 2816 * 1024 / 4);

  embed_kernel<<<2048, 256, 0, stream>>>(ids, emb_f, x);
  for (int l = 0; l < 4; ++l) {
    rmsnorm_kernel<<<2048, 256, 0, stream>>>(x, ln1 + l * 1024, h);
    qkv_gemm<<<192, 256, 0, stream>>>(
        h, qw_b + (size_t)l * 1024 * 1024, kvw_b + (size_t)l * 512 * 1024,
        q_b + l * 1024, kv_b + l * 512, qb, kvb);
    attn_kernel<<<dim3(8, 16, 4), 256, 0, stream>>>(qb, kvb, ao);
    gemm_bt<4, 16, 8, 2><<<256, 256, 0, stream>>>(
        ao, ow_b + (size_t)l * 1024 * 1024, x, 1024, 1024);
    rmsnorm_kernel<<<2048, 256, 0, stream>>>(x, ln2 + l * 1024, h);
    gateup_gemm<<<704, 256, 0, stream>>>(
        h, gw_b + (size_t)l * 2816 * 1024, uw_b + (size_t)l * 2816 * 1024, gb, ub);
    down_gemm<<<256, 256, 0, stream>>>(
        gb, ub, dw_b + (size_t)l * 1024 * 2816, x);
  }
  rmsnorm_kernel<<<2048, 256, 0, stream>>>(x, lw, h);
  lmhead_gemm<<<1000, 512, 0, stream>>>(h, emb_b, out);
}